// Round 1
// baseline (6140.681 us; speedup 1.0000x reference)
//
#include <hip/hip_runtime.h>
#include <math.h>

#define BB   4
#define NN   10000
#define EE   160000
#define DD   128
#define OUTD 64
#define LL   4
#define NEGS 0.01f

__device__ __forceinline__ float lrelu(float x) { return x > 0.0f ? x : NEGS * x; }

// h = lrelu(pos @ w0 + b0), one thread per (b,n,d)
__global__ void k_h0(const float* __restrict__ x, const float* __restrict__ w0,
                     const float* __restrict__ b0, float* __restrict__ h) {
    int idx = blockIdx.x * blockDim.x + threadIdx.x;
    if (idx >= BB * NN * DD) return;
    int d  = idx & (DD - 1);
    int bn = idx >> 7;
    const float* p = x + (size_t)bn * 3;
    float s = b0[d] + p[0] * w0[0 * DD + d] + p[1] * w0[1 * DD + d] + p[2] * w0[2 * DD + d];
    h[idx] = lrelu(s);
}

__global__ void k_count(const int* __restrict__ col, float* __restrict__ cnt) {
    int e = blockIdx.x * blockDim.x + threadIdx.x;
    if (e < EE) atomicAdd(&cnt[col[e]], 1.0f);
}

// ---------------- edge MLP + scatter-add ----------------
// Tile: 32 edges x 128 outputs. 256 threads: d = t&127, row-half = t>>7 (16 rows each).
#define ET  32
#define ERT 16

__global__ __launch_bounds__(256) void k_edge(
    const float* __restrict__ pos, const float* __restrict__ h,
    const int* __restrict__ row, const int* __restrict__ col,
    const float* __restrict__ w1, const float* __restrict__ b1,
    const float* __restrict__ w2, const float* __restrict__ b2,
    float* __restrict__ aggr)
{
    __shared__ float s_in[ET * 257];   // [h_row | h_col | dist_sq]
    __shared__ float s_mid[ET * DD];
    __shared__ int   s_col[ET];
    const int b  = blockIdx.y;
    const int e0 = blockIdx.x * ET;
    const int t  = threadIdx.x;
    const int d  = t & (DD - 1);
    const int rh = t >> 7;

    // stage edge_in: half the threads fetch h[row], other half h[col]
    for (int j = 0; j < ET; ++j) {
        int e   = e0 + j;
        int src = (rh == 0) ? row[e] : col[e];
        s_in[j * 257 + rh * DD + d] = h[((size_t)b * NN + src) * DD + d];
    }
    if (t < ET) {
        int e = e0 + t;
        int r = row[e], c = col[e];
        s_col[t] = c;
        const float* pr = pos + ((size_t)b * NN + r) * 3;
        const float* pc = pos + ((size_t)b * NN + c) * 3;
        float dx = pr[0] - pc[0], dy = pr[1] - pc[1], dz = pr[2] - pc[2];
        s_in[t * 257 + 256] = dx * dx + dy * dy + dz * dz;
    }
    __syncthreads();

    float acc[ERT];
    {
        float bias = b1[d];
        #pragma unroll
        for (int j = 0; j < ERT; ++j) acc[j] = bias;
    }
    const float* sA = s_in + rh * ERT * 257;
    for (int k = 0; k < 256; k += 4) {
        float wa = w1[(k + 0) * DD + d];
        float wb = w1[(k + 1) * DD + d];
        float wc = w1[(k + 2) * DD + d];
        float wd = w1[(k + 3) * DD + d];
        #pragma unroll
        for (int j = 0; j < ERT; ++j) {
            acc[j] += sA[j * 257 + k + 0] * wa;
            acc[j] += sA[j * 257 + k + 1] * wb;
            acc[j] += sA[j * 257 + k + 2] * wc;
            acc[j] += sA[j * 257 + k + 3] * wd;
        }
    }
    {   // k = 256 (dist_sq column)
        float wa = w1[256 * DD + d];
        #pragma unroll
        for (int j = 0; j < ERT; ++j) acc[j] += sA[j * 257 + 256] * wa;
    }
    #pragma unroll
    for (int j = 0; j < ERT; ++j)
        s_mid[(rh * ERT + j) * DD + d] = lrelu(acc[j]);
    __syncthreads();

    {
        float bias = b2[d];
        #pragma unroll
        for (int j = 0; j < ERT; ++j) acc[j] = bias;
    }
    const float* sM = s_mid + rh * ERT * DD;
    for (int k = 0; k < DD; k += 4) {
        float wa = w2[(k + 0) * DD + d];
        float wb = w2[(k + 1) * DD + d];
        float wc = w2[(k + 2) * DD + d];
        float wd = w2[(k + 3) * DD + d];
        #pragma unroll
        for (int j = 0; j < ERT; ++j) {
            acc[j] += sM[j * DD + k + 0] * wa;
            acc[j] += sM[j * DD + k + 1] * wb;
            acc[j] += sM[j * DD + k + 2] * wc;
            acc[j] += sM[j * DD + k + 3] * wd;
        }
    }
    #pragma unroll
    for (int j = 0; j < ERT; ++j) {
        float v = lrelu(acc[j]);
        int   c = s_col[rh * ERT + j];
        atomicAdd(&aggr[((size_t)b * NN + c) * DD + d], v);
    }
}

// ---------------- node MLP + coord/pos update ----------------
// Tile: 16 nodes x 128 outputs. 256 threads: d = t&127, half = t>>7 (8 rows each).
#define NT  16
#define NRT 8

__global__ __launch_bounds__(256) void k_node(
    const float* __restrict__ aggr, const float* __restrict__ cnt,
    const float* __restrict__ cw, const float* __restrict__ cb,
    const float* __restrict__ w1, const float* __restrict__ b1,
    const float* __restrict__ w2, const float* __restrict__ b2,
    float* __restrict__ pos, float* __restrict__ h)
{
    __shared__ float s_in[NT * 256];   // [h | aggr_mean]
    __shared__ float s_mid[NT * DD];
    __shared__ float s_cu[NT];
    const int b    = blockIdx.y;
    const int n0   = blockIdx.x * NT;
    const int t    = threadIdx.x;
    const int d    = t & (DD - 1);
    const int half = t >> 7;

    for (int j = 0; j < NT; ++j) {
        int n = n0 + j;
        if (half == 0) {
            s_in[j * 256 + d] = h[((size_t)b * NN + n) * DD + d];
        } else {
            float dn = cnt[n];
            dn = dn > 1.0f ? dn : 1.0f;
            s_in[j * 256 + DD + d] = aggr[((size_t)b * NN + n) * DD + d] / dn;
        }
    }
    __syncthreads();

    // coord_update = tanh(aggr_mean . cw + cb); wave-shuffle reduce, 4 nodes/wave
    const int wv = t >> 6, lane = t & 63;
    for (int j = 0; j < NT / 4; ++j) {
        int n = wv * (NT / 4) + j;
        float p = s_in[n * 256 + DD + lane] * cw[lane]
                + s_in[n * 256 + DD + 64 + lane] * cw[64 + lane];
        #pragma unroll
        for (int off = 32; off > 0; off >>= 1) p += __shfl_down(p, off);
        if (lane == 0) s_cu[n] = tanhf(p + cb[0]);
    }
    __syncthreads();
    if (t < NT * 3) {
        int n = t / 3, c = t - n * 3;
        pos[((size_t)b * NN + n0 + n) * 3 + c] += 0.1f * s_cu[n];
    }

    float acc[NRT];
    {
        float bias = b1[d];
        #pragma unroll
        for (int j = 0; j < NRT; ++j) acc[j] = bias;
    }
    const float* sA = s_in + half * NRT * 256;
    for (int k = 0; k < 256; k += 4) {
        float wa = w1[(k + 0) * DD + d];
        float wb = w1[(k + 1) * DD + d];
        float wc = w1[(k + 2) * DD + d];
        float wd = w1[(k + 3) * DD + d];
        #pragma unroll
        for (int j = 0; j < NRT; ++j) {
            acc[j] += sA[j * 256 + k + 0] * wa;
            acc[j] += sA[j * 256 + k + 1] * wb;
            acc[j] += sA[j * 256 + k + 2] * wc;
            acc[j] += sA[j * 256 + k + 3] * wd;
        }
    }
    #pragma unroll
    for (int j = 0; j < NRT; ++j)
        s_mid[(half * NRT + j) * DD + d] = lrelu(acc[j]);
    __syncthreads();

    {
        float bias = b2[d];
        #pragma unroll
        for (int j = 0; j < NRT; ++j) acc[j] = bias;
    }
    const float* sM = s_mid + half * NRT * DD;
    for (int k = 0; k < DD; k += 4) {
        float wa = w2[(k + 0) * DD + d];
        float wb = w2[(k + 1) * DD + d];
        float wc = w2[(k + 2) * DD + d];
        float wd = w2[(k + 3) * DD + d];
        #pragma unroll
        for (int j = 0; j < NRT; ++j) {
            acc[j] += sM[j * DD + k + 0] * wa;
            acc[j] += sM[j * DD + k + 1] * wb;
            acc[j] += sM[j * DD + k + 2] * wc;
            acc[j] += sM[j * DD + k + 3] * wd;
        }
    }
    #pragma unroll
    for (int j = 0; j < NRT; ++j) {
        int r = half * NRT + j;
        float v = lrelu(acc[j]);
        h[((size_t)b * NN + n0 + r) * DD + d] = s_in[r * 256 + d] + v;
    }
}

// partial sums of h over nodes -> hm[b*DD+d] (atomic)
#define NPC 50
__global__ void k_mean(const float* __restrict__ h, float* __restrict__ hm) {
    int b  = blockIdx.y;
    int n0 = blockIdx.x * NPC;
    int d  = threadIdx.x;
    float s = 0.0f;
    for (int n = n0; n < n0 + NPC; ++n) s += h[((size_t)b * NN + n) * DD + d];
    atomicAdd(&hm[b * DD + d], s);
}

__global__ void k_proj(const float* __restrict__ hm, const float* __restrict__ wp,
                       const float* __restrict__ bp, float* __restrict__ out) {
    int t = threadIdx.x;            // 256 = B*OUT
    int b = t >> 6, o = t & (OUTD - 1);
    float s = 0.0f;
    for (int d2 = 0; d2 < DD; ++d2) s += hm[b * DD + d2] * wp[d2 * OUTD + o];
    s = s * (1.0f / NN) + bp[o];
    out[b * OUTD + o] = lrelu(s);
}

extern "C" void kernel_launch(void* const* d_in, const int* in_sizes, int n_in,
                              void* d_out, int out_size, void* d_ws, size_t ws_size,
                              hipStream_t stream) {
    (void)in_sizes; (void)n_in; (void)out_size; (void)ws_size;
    const float* x   = (const float*)d_in[0];
    const int*   ei  = (const int*)d_in[1];
    const float* w0  = (const float*)d_in[2];
    const float* b0  = (const float*)d_in[3];
    const float* ew1 = (const float*)d_in[4];
    const float* eb1 = (const float*)d_in[5];
    const float* ew2 = (const float*)d_in[6];
    const float* eb2 = (const float*)d_in[7];
    const float* cw  = (const float*)d_in[8];
    const float* cb  = (const float*)d_in[9];
    const float* nw1 = (const float*)d_in[10];
    const float* nb1 = (const float*)d_in[11];
    const float* nw2 = (const float*)d_in[12];
    const float* nb2 = (const float*)d_in[13];
    const float* wp  = (const float*)d_in[14];
    const float* bp  = (const float*)d_in[15];
    const int* row = ei;
    const int* col = ei + EE;

    float* ws   = (float*)d_ws;
    float* h    = ws;                              // B*N*D = 5,120,000
    float* aggr = h    + (size_t)BB * NN * DD;     // B*N*D
    float* pos  = aggr + (size_t)BB * NN * DD;     // B*N*3
    float* cnt  = pos  + (size_t)BB * NN * 3;      // N
    float* hm   = cnt  + NN;                       // B*D

    hipMemcpyAsync(pos, x, sizeof(float) * (size_t)BB * NN * 3,
                   hipMemcpyDeviceToDevice, stream);
    hipMemsetAsync(cnt, 0, sizeof(float) * NN, stream);
    hipMemsetAsync(hm, 0, sizeof(float) * BB * DD, stream);

    k_h0<<<(BB * NN * DD + 255) / 256, 256, 0, stream>>>(x, w0, b0, h);
    k_count<<<(EE + 255) / 256, 256, 0, stream>>>(col, cnt);

    for (int i = 0; i < LL; ++i) {
        hipMemsetAsync(aggr, 0, sizeof(float) * (size_t)BB * NN * DD, stream);
        k_edge<<<dim3(EE / ET, BB), 256, 0, stream>>>(
            pos, h, row, col,
            ew1 + (size_t)i * 257 * DD, eb1 + (size_t)i * DD,
            ew2 + (size_t)i * DD * DD,  eb2 + (size_t)i * DD,
            aggr);
        k_node<<<dim3(NN / NT, BB), 256, 0, stream>>>(
            aggr, cnt,
            cw + (size_t)i * DD, cb + i,
            nw1 + (size_t)i * 2 * DD * DD, nb1 + (size_t)i * DD,
            nw2 + (size_t)i * DD * DD,     nb2 + (size_t)i * DD,
            pos, h);
    }

    k_mean<<<dim3(NN / NPC, BB), DD, 0, stream>>>(h, hm);
    k_proj<<<1, 256, 0, stream>>>(hm, wp, bp, (float*)d_out);
}

// Round 2
// 1427.358 us; speedup vs baseline: 4.3021x; 4.3021x over previous
//
#include <hip/hip_runtime.h>
#include <hip/hip_bf16.h>
#include <math.h>

#define BB   4
#define NN   10000
#define NP   10112          // NN padded to multiple of 128
#define EE   160000
#define DD   128
#define OUTD 64
#define LL   4
#define NEGS 0.01f
#define MSTR 136            // s_mid row stride (bf16 elems): 272B, 16B-multiple, conflict-light

typedef __attribute__((ext_vector_type(8))) short   short8;   // 8 bf16 = 4 VGPRs
typedef __attribute__((ext_vector_type(4))) float   floatx4;

__device__ __forceinline__ float lrelu(float x) { return x > 0.0f ? x : NEGS * x; }
__device__ __forceinline__ ushort f2bf(float x) {
    __hip_bfloat16 b = __float2bfloat16(x);
    return *reinterpret_cast<ushort*>(&b);
}

// ---- weights -> MFMA B-fragment layout: dst[l][ks][nt][lane][j] = W[l][ks*32+quad*8+j][nt*16+l16]
__global__ void k_cvtw(const float* __restrict__ src, ushort* __restrict__ dst,
                       int rowpitch, int nks) {
    int tid = blockIdx.x * 256 + threadIdx.x;
    if (tid >= LL * nks * 512) return;
    int lane = tid & 63;
    int nt   = (tid >> 6) & 7;
    int ks   = (tid >> 9) % nks;
    int l    = tid / (nks * 512);
    int quad = lane >> 4, l16 = lane & 15;
    int n = nt * 16 + l16;
    const float* s = src + (size_t)l * rowpitch * DD;
    ushort* d = dst + (size_t)tid * 8;
    #pragma unroll
    for (int j = 0; j < 8; ++j)
        d[j] = f2bf(s[(size_t)(ks * 32 + quad * 8 + j) * DD + n]);
}

// h = lrelu(pos @ w0 + b0); fp32 master + bf16 copy; zero pad rows
__global__ void k_h0(const float* __restrict__ x, const float* __restrict__ w0,
                     const float* __restrict__ b0, float* __restrict__ h,
                     ushort* __restrict__ hb) {
    int idx = blockIdx.x * 256 + threadIdx.x;
    if (idx >= BB * NP * DD) return;
    int d  = idx & (DD - 1);
    int bn = idx >> 7;
    int n  = bn % NP, b = bn / NP;
    float v = 0.0f;
    if (n < NN) {
        const float* p = x + ((size_t)b * NN + n) * 3;
        v = lrelu(b0[d] + p[0] * w0[d] + p[1] * w0[DD + d] + p[2] * w0[2 * DD + d]);
    }
    h[idx] = v;
    hb[idx] = f2bf(v);
}

__global__ void k_count(const int* __restrict__ col, float* __restrict__ cnt) {
    int e = blockIdx.x * blockDim.x + threadIdx.x;
    if (e < EE) atomicAdd(&cnt[col[e]], 1.0f);
}

// ---------------- edge MLP (bf16 MFMA) + fp32 scatter-add ----------------
// block = 256 thr = 4 waves; 128 edges/block; wave w: edges [w*32, w*32+32) x 128 cols
__global__ __launch_bounds__(256) void k_edge(
    const float* __restrict__ pos, const ushort* __restrict__ hb,
    const int* __restrict__ row, const int* __restrict__ col,
    const ushort* __restrict__ w1f, const float* __restrict__ w1last,
    const float* __restrict__ b1,
    const ushort* __restrict__ w2f, const float* __restrict__ b2,
    float* __restrict__ aggr)
{
    __shared__ int   s_row[128];
    __shared__ int   s_col[128];
    __shared__ float s_ds[128];
    __shared__ __align__(16) ushort s_mid[128 * MSTR];

    const int b    = blockIdx.y;
    const int e0   = blockIdx.x * 128;
    const int t    = threadIdx.x;
    const int w    = t >> 6, lane = t & 63;
    const int quad = lane >> 4, l16 = lane & 15;

    if (t < 128) {
        int e = e0 + t;
        int r = row[e], c = col[e];
        s_row[t] = r;
        s_col[t] = c;
        const float* pr = pos + ((size_t)b * NN + r) * 3;
        const float* pc = pos + ((size_t)b * NN + c) * 3;
        float dx = pr[0] - pc[0], dy = pr[1] - pc[1], dz = pr[2] - pc[2];
        s_ds[t] = dx * dx + dy * dy + dz * dz;
    }
    __syncthreads();

    const int ew = w * 32;
    const ushort* aptr[2][2];
    #pragma unroll
    for (int mt = 0; mt < 2; ++mt) {
        int el = ew + mt * 16 + l16;
        aptr[mt][0] = hb + ((size_t)b * NP + s_row[el]) * DD;   // k in [0,128)
        aptr[mt][1] = hb + ((size_t)b * NP + s_col[el]) * DD;   // k in [128,256)
    }
    float b1r[8], w1r[8], b2r[8];
    #pragma unroll
    for (int nt = 0; nt < 8; ++nt) {
        int d = nt * 16 + l16;
        b1r[nt] = b1[d]; w1r[nt] = w1last[d]; b2r[nt] = b2[d];
    }
    float dsr[2][4];
    #pragma unroll
    for (int mt = 0; mt < 2; ++mt)
        #pragma unroll
        for (int r = 0; r < 4; ++r) dsr[mt][r] = s_ds[ew + mt * 16 + quad * 4 + r];

    // GEMM1: acc init folds bias + dist_sq * w1[256,:]
    floatx4 acc[2][8];
    #pragma unroll
    for (int mt = 0; mt < 2; ++mt)
        #pragma unroll
        for (int nt = 0; nt < 8; ++nt)
            #pragma unroll
            for (int r = 0; r < 4; ++r)
                acc[mt][nt][r] = b1r[nt] + dsr[mt][r] * w1r[nt];

    const short8* w1v = (const short8*)w1f;
    #pragma unroll
    for (int ks = 0; ks < 8; ++ks) {
        short8 bf[8];
        #pragma unroll
        for (int nt = 0; nt < 8; ++nt) bf[nt] = w1v[(ks * 8 + nt) * 64 + lane];
        const int half = ks >> 2;
        const int koff = (ks & 3) * 32 + quad * 8;
        #pragma unroll
        for (int mt = 0; mt < 2; ++mt) {
            short8 af = *(const short8*)(aptr[mt][half] + koff);
            #pragma unroll
            for (int nt = 0; nt < 8; ++nt)
                acc[mt][nt] = __builtin_amdgcn_mfma_f32_16x16x32_bf16(af, bf[nt], acc[mt][nt], 0, 0, 0);
        }
    }

    // lrelu -> s_mid (bf16, wave-private rows; no block barrier needed)
    #pragma unroll
    for (int mt = 0; mt < 2; ++mt)
        #pragma unroll
        for (int nt = 0; nt < 8; ++nt)
            #pragma unroll
            for (int r = 0; r < 4; ++r)
                s_mid[(ew + mt * 16 + quad * 4 + r) * MSTR + nt * 16 + l16] =
                    f2bf(lrelu(acc[mt][nt][r]));

    // GEMM2
    floatx4 acc2[2][8];
    #pragma unroll
    for (int mt = 0; mt < 2; ++mt)
        #pragma unroll
        for (int nt = 0; nt < 8; ++nt)
            #pragma unroll
            for (int r = 0; r < 4; ++r) acc2[mt][nt][r] = b2r[nt];

    const short8* w2v = (const short8*)w2f;
    #pragma unroll
    for (int ks = 0; ks < 4; ++ks) {
        short8 bf[8];
        #pragma unroll
        for (int nt = 0; nt < 8; ++nt) bf[nt] = w2v[(ks * 8 + nt) * 64 + lane];
        const int koff = ks * 32 + quad * 8;
        #pragma unroll
        for (int mt = 0; mt < 2; ++mt) {
            short8 af = *(const short8*)(&s_mid[(ew + mt * 16 + l16) * MSTR + koff]);
            #pragma unroll
            for (int nt = 0; nt < 8; ++nt)
                acc2[mt][nt] = __builtin_amdgcn_mfma_f32_16x16x32_bf16(af, bf[nt], acc2[mt][nt], 0, 0, 0);
        }
    }

    // scatter-add msg into aggr (fp32 atomics)
    #pragma unroll
    for (int mt = 0; mt < 2; ++mt)
        #pragma unroll
        for (int r = 0; r < 4; ++r) {
            int el = ew + mt * 16 + quad * 4 + r;
            float* dst = aggr + ((size_t)b * NP + s_col[el]) * DD;
            #pragma unroll
            for (int nt = 0; nt < 8; ++nt)
                atomicAdd(dst + nt * 16 + l16, lrelu(acc2[mt][nt][r]));
        }
}

// aggr -> aggr_mean (bf16) + coord/pos update
__global__ void k_aggr(const float* __restrict__ aggr, const float* __restrict__ cnt,
                       const float* __restrict__ cw, const float* __restrict__ cb,
                       float* __restrict__ pos, ushort* __restrict__ amb) {
    int b = blockIdx.y;
    int w = threadIdx.x >> 6, lane = threadIdx.x & 63;
    int n = blockIdx.x * 4 + w;
    if (n >= NN) return;
    float dn = cnt[n];
    dn = dn > 1.0f ? dn : 1.0f;
    float inv = 1.0f / dn;
    size_t base = ((size_t)b * NP + n) * DD;
    float a0 = aggr[base + lane] * inv;
    float a1 = aggr[base + 64 + lane] * inv;
    amb[base + lane] = f2bf(a0);
    amb[base + 64 + lane] = f2bf(a1);
    float p = a0 * cw[lane] + a1 * cw[64 + lane];
    #pragma unroll
    for (int off = 32; off > 0; off >>= 1) p += __shfl_down(p, off);
    if (lane == 0) {
        float cu = 0.1f * tanhf(p + cb[0]);
        float* pp = pos + ((size_t)b * NN + n) * 3;
        pp[0] += cu; pp[1] += cu; pp[2] += cu;
    }
}

// ---------------- node MLP (bf16 MFMA) + residual ----------------
__global__ __launch_bounds__(256) void k_node(
    ushort* hb, const ushort* __restrict__ amb,
    const ushort* __restrict__ w1f, const float* __restrict__ b1,
    const ushort* __restrict__ w2f, const float* __restrict__ b2,
    float* h)
{
    __shared__ __align__(16) ushort s_mid[128 * MSTR];

    const int b    = blockIdx.y;
    const int n0   = blockIdx.x * 128;
    const int t    = threadIdx.x;
    const int w    = t >> 6, lane = t & 63;
    const int quad = lane >> 4, l16 = lane & 15;
    const int ew   = w * 32;

    const ushort* aptr[2][2];
    #pragma unroll
    for (int mt = 0; mt < 2; ++mt) {
        size_t base = ((size_t)b * NP + n0 + ew + mt * 16 + l16) * DD;
        aptr[mt][0] = hb + base;     // k in [0,128): h
        aptr[mt][1] = amb + base;    // k in [128,256): aggr_mean
    }
    float b1r[8], b2r[8];
    #pragma unroll
    for (int nt = 0; nt < 8; ++nt) {
        int d = nt * 16 + l16;
        b1r[nt] = b1[d]; b2r[nt] = b2[d];
    }

    floatx4 acc[2][8];
    #pragma unroll
    for (int mt = 0; mt < 2; ++mt)
        #pragma unroll
        for (int nt = 0; nt < 8; ++nt)
            #pragma unroll
            for (int r = 0; r < 4; ++r) acc[mt][nt][r] = b1r[nt];

    const short8* w1v = (const short8*)w1f;
    #pragma unroll
    for (int ks = 0; ks < 8; ++ks) {
        short8 bf[8];
        #pragma unroll
        for (int nt = 0; nt < 8; ++nt) bf[nt] = w1v[(ks * 8 + nt) * 64 + lane];
        const int half = ks >> 2;
        const int koff = (ks & 3) * 32 + quad * 8;
        #pragma unroll
        for (int mt = 0; mt < 2; ++mt) {
            short8 af = *(const short8*)(aptr[mt][half] + koff);
            #pragma unroll
            for (int nt = 0; nt < 8; ++nt)
                acc[mt][nt] = __builtin_amdgcn_mfma_f32_16x16x32_bf16(af, bf[nt], acc[mt][nt], 0, 0, 0);
        }
    }

    #pragma unroll
    for (int mt = 0; mt < 2; ++mt)
        #pragma unroll
        for (int nt = 0; nt < 8; ++nt)
            #pragma unroll
            for (int r = 0; r < 4; ++r)
                s_mid[(ew + mt * 16 + quad * 4 + r) * MSTR + nt * 16 + l16] =
                    f2bf(lrelu(acc[mt][nt][r]));

    floatx4 acc2[2][8];
    #pragma unroll
    for (int mt = 0; mt < 2; ++mt)
        #pragma unroll
        for (int nt = 0; nt < 8; ++nt)
            #pragma unroll
            for (int r = 0; r < 4; ++r) acc2[mt][nt][r] = b2r[nt];

    const short8* w2v = (const short8*)w2f;
    #pragma unroll
    for (int ks = 0; ks < 4; ++ks) {
        short8 bf[8];
        #pragma unroll
        for (int nt = 0; nt < 8; ++nt) bf[nt] = w2v[(ks * 8 + nt) * 64 + lane];
        const int koff = ks * 32 + quad * 8;
        #pragma unroll
        for (int mt = 0; mt < 2; ++mt) {
            short8 af = *(const short8*)(&s_mid[(ew + mt * 16 + l16) * MSTR + koff]);
            #pragma unroll
            for (int nt = 0; nt < 8; ++nt)
                acc2[mt][nt] = __builtin_amdgcn_mfma_f32_16x16x32_bf16(af, bf[nt], acc2[mt][nt], 0, 0, 0);
        }
    }

    // h += lrelu(.); write fp32 master + bf16 copy (wave-private rows, no races)
    #pragma unroll
    for (int mt = 0; mt < 2; ++mt)
        #pragma unroll
        for (int r = 0; r < 4; ++r) {
            int n = n0 + ew + mt * 16 + quad * 4 + r;
            if (n < NN) {
                size_t base = ((size_t)b * NP + n) * DD;
                #pragma unroll
                for (int nt = 0; nt < 8; ++nt) {
                    int d = nt * 16 + l16;
                    float hv = h[base + d] + lrelu(acc2[mt][nt][r]);
                    h[base + d] = hv;
                    hb[base + d] = f2bf(hv);
                }
            }
        }
}

#define NPC 50
__global__ void k_mean(const float* __restrict__ h, float* __restrict__ hm) {
    int b  = blockIdx.y;
    int n0 = blockIdx.x * NPC;
    int d  = threadIdx.x;
    float s = 0.0f;
    for (int n = n0; n < n0 + NPC; ++n) s += h[((size_t)b * NP + n) * DD + d];
    atomicAdd(&hm[b * DD + d], s);
}

__global__ void k_proj(const float* __restrict__ hm, const float* __restrict__ wp,
                       const float* __restrict__ bp, float* __restrict__ out) {
    int t = threadIdx.x;
    int b = t >> 6, o = t & (OUTD - 1);
    float s = 0.0f;
    for (int d2 = 0; d2 < DD; ++d2) s += hm[b * DD + d2] * wp[d2 * OUTD + o];
    s = s * (1.0f / NN) + bp[o];
    out[b * OUTD + o] = lrelu(s);
}

extern "C" void kernel_launch(void* const* d_in, const int* in_sizes, int n_in,
                              void* d_out, int out_size, void* d_ws, size_t ws_size,
                              hipStream_t stream) {
    (void)in_sizes; (void)n_in; (void)out_size; (void)ws_size;
    const float* x   = (const float*)d_in[0];
    const int*   ei  = (const int*)d_in[1];
    const float* w0  = (const float*)d_in[2];
    const float* b0  = (const float*)d_in[3];
    const float* ew1 = (const float*)d_in[4];
    const float* eb1 = (const float*)d_in[5];
    const float* ew2 = (const float*)d_in[6];
    const float* eb2 = (const float*)d_in[7];
    const float* cw  = (const float*)d_in[8];
    const float* cb  = (const float*)d_in[9];
    const float* nw1 = (const float*)d_in[10];
    const float* nb1 = (const float*)d_in[11];
    const float* nw2 = (const float*)d_in[12];
    const float* nb2 = (const float*)d_in[13];
    const float* wp  = (const float*)d_in[14];
    const float* bp  = (const float*)d_in[15];
    const int* row = ei;
    const int* col = ei + EE;

    const size_t HSZ = (size_t)BB * NP * DD;          // 5,177,344
    float* ws   = (float*)d_ws;
    float* h    = ws;
    float* aggr = h + HSZ;
    float* pos  = aggr + HSZ;                          // B*N*3
    float* cnt  = pos + (size_t)BB * NN * 3;
    float* hm   = cnt + NN;
    ushort* hb   = (ushort*)(hm + 512);
    ushort* amb  = hb + HSZ;
    ushort* ew1f = amb + HSZ;                          // L*8*8*64*8 = 131072
    ushort* ew2f = ew1f + (size_t)LL * 32768;          // L*4*8*64*8 = 65536
    ushort* nw1f = ew2f + (size_t)LL * 16384;
    ushort* nw2f = nw1f + (size_t)LL * 32768;

    hipMemcpyAsync(pos, x, sizeof(float) * (size_t)BB * NN * 3,
                   hipMemcpyDeviceToDevice, stream);
    hipMemsetAsync(cnt, 0, sizeof(float) * NN, stream);
    hipMemsetAsync(hm, 0, sizeof(float) * BB * DD, stream);

    // weight conversion to fragment layout (tiny)
    k_cvtw<<<(LL * 8 * 512 + 255) / 256, 256, 0, stream>>>(ew1, ew1f, 257, 8);
    k_cvtw<<<(LL * 4 * 512 + 255) / 256, 256, 0, stream>>>(ew2, ew2f, 128, 4);
    k_cvtw<<<(LL * 8 * 512 + 255) / 256, 256, 0, stream>>>(nw1, nw1f, 256, 8);
    k_cvtw<<<(LL * 4 * 512 + 255) / 256, 256, 0, stream>>>(nw2, nw2f, 128, 4);

    k_h0<<<((int)HSZ + 255) / 256, 256, 0, stream>>>(x, w0, b0, h, hb);
    k_count<<<(EE + 255) / 256, 256, 0, stream>>>(col, cnt);

    for (int i = 0; i < LL; ++i) {
        hipMemsetAsync(aggr, 0, sizeof(float) * HSZ, stream);
        k_edge<<<dim3(EE / 128, BB), 256, 0, stream>>>(
            pos, hb, row, col,
            ew1f + (size_t)i * 32768,
            ew1 + (size_t)i * 257 * DD + (size_t)256 * DD,   // w1last (k=256 row, fp32)
            eb1 + (size_t)i * DD,
            ew2f + (size_t)i * 16384,
            eb2 + (size_t)i * DD,
            aggr);
        k_aggr<<<dim3((NN + 3) / 4, BB), 256, 0, stream>>>(
            aggr, cnt, cw + (size_t)i * DD, cb + i, pos, amb);
        k_node<<<dim3(NP / 128, BB), 256, 0, stream>>>(
            hb, amb,
            nw1f + (size_t)i * 32768, nb1 + (size_t)i * DD,
            nw2f + (size_t)i * 16384, nb2 + (size_t)i * DD,
            h);
    }

    k_mean<<<dim3(NN / NPC, BB), DD, 0, stream>>>(h, hm);
    k_proj<<<1, 256, 0, stream>>>(hm, wp, bp, (float*)d_out);
}

// Round 3
// 901.527 us; speedup vs baseline: 6.8114x; 1.5833x over previous
//
#include <hip/hip_runtime.h>
#include <hip/hip_bf16.h>
#include <math.h>

#define BB   4
#define NN   10000
#define NP   10112          // NN padded to multiple of 128
#define EE   160000         // = 1250 * 128, no edge padding needed
#define DD   128
#define OUTD 64
#define LL   4
#define NEGS 0.01f
#define MSTR 136            // s_mid row stride (bf16 elems)
#define RSTR 65             // s_red row stride (fp32 elems)

typedef __attribute__((ext_vector_type(8))) short   short8;
typedef __attribute__((ext_vector_type(4))) float   floatx4;

__device__ __forceinline__ float lrelu(float x) { return x > 0.0f ? x : NEGS * x; }
__device__ __forceinline__ ushort f2bf(float x) {
    __hip_bfloat16 b = __float2bfloat16(x);
    return *reinterpret_cast<ushort*>(&b);
}

// ---- weights -> MFMA B-fragment layout
__global__ void k_cvtw(const float* __restrict__ src, ushort* __restrict__ dst,
                       int rowpitch, int nks) {
    int tid = blockIdx.x * 256 + threadIdx.x;
    if (tid >= LL * nks * 512) return;
    int lane = tid & 63;
    int nt   = (tid >> 6) & 7;
    int ks   = (tid >> 9) % nks;
    int l    = tid / (nks * 512);
    int quad = lane >> 4, l16 = lane & 15;
    int n = nt * 16 + l16;
    const float* s = src + (size_t)l * rowpitch * DD;
    ushort* d = dst + (size_t)tid * 8;
    #pragma unroll
    for (int j = 0; j < 8; ++j)
        d[j] = f2bf(s[(size_t)(ks * 32 + quad * 8 + j) * DD + n]);
}

__global__ void k_h0(const float* __restrict__ x, const float* __restrict__ w0,
                     const float* __restrict__ b0, float* __restrict__ h,
                     ushort* __restrict__ hb) {
    int idx = blockIdx.x * 256 + threadIdx.x;
    if (idx >= BB * NP * DD) return;
    int d  = idx & (DD - 1);
    int bn = idx >> 7;
    int n  = bn % NP, b = bn / NP;
    float v = 0.0f;
    if (n < NN) {
        const float* p = x + ((size_t)b * NN + n) * 3;
        v = lrelu(b0[d] + p[0] * w0[d] + p[1] * w0[DD + d] + p[2] * w0[2 * DD + d]);
    }
    h[idx] = v;
    hb[idx] = f2bf(v);
}

// per-col counts: float (denom) + int (sort offsets)
__global__ void k_count(const int* __restrict__ col, float* __restrict__ cnt,
                        int* __restrict__ ecnt) {
    int e = blockIdx.x * blockDim.x + threadIdx.x;
    if (e < EE) {
        int c = col[e];
        atomicAdd(&cnt[c], 1.0f);
        atomicAdd(&ecnt[c], 1);
    }
}

// exclusive prefix scan of ecnt[0..NN) -> cursor  (one block, 256 threads, chunks of 40)
__global__ __launch_bounds__(256) void k_scan(const int* __restrict__ ecnt,
                                              int* __restrict__ cursor) {
    __shared__ int s_sum[256];
    int t = threadIdx.x;
    int base = t * 40;
    int s = 0;
    for (int i = 0; i < 40; ++i) {
        int n = base + i;
        if (n < NN) s += ecnt[n];
    }
    s_sum[t] = s;
    __syncthreads();
    if (t == 0) {
        int a = 0;
        for (int i = 0; i < 256; ++i) { int v = s_sum[i]; s_sum[i] = a; a += v; }
    }
    __syncthreads();
    int a = s_sum[t];
    for (int i = 0; i < 40; ++i) {
        int n = base + i;
        if (n < NN) { cursor[n] = a; a += ecnt[n]; }
    }
}

// place edges into col-sorted order
__global__ void k_place(const int* __restrict__ row, const int* __restrict__ col,
                        int* __restrict__ cursor,
                        int* __restrict__ rowS, int* __restrict__ colS) {
    int e = blockIdx.x * blockDim.x + threadIdx.x;
    if (e >= EE) return;
    int c = col[e];
    int p = atomicAdd(&cursor[c], 1);
    rowS[p] = row[e];
    colS[p] = c;
}

// ---------------- edge MLP (bf16 MFMA) + segmented reduction ----------------
// 256 thr = 4 waves; 128 col-sorted edges/block; wave w owns edges [w*32, w*32+32)
__global__ __launch_bounds__(256) void k_edge(
    const float* __restrict__ pos, const ushort* __restrict__ hb,
    const int* __restrict__ rowS, const int* __restrict__ colS,
    const ushort* __restrict__ w1f, const float* __restrict__ w1last,
    const float* __restrict__ b1,
    const ushort* __restrict__ w2f, const float* __restrict__ b2,
    float* __restrict__ aggr)
{
    __shared__ int   s_row[128];
    __shared__ int   s_col[128];
    __shared__ float s_ds[128];
    __shared__ __align__(16) ushort s_buf[128 * MSTR];   // s_mid, reused as s_red

    const int b    = blockIdx.y;
    const int e0   = blockIdx.x * 128;
    const int t    = threadIdx.x;
    const int w    = t >> 6, lane = t & 63;
    const int quad = lane >> 4, l16 = lane & 15;

    if (t < 128) {
        int e = e0 + t;
        int r = rowS[e], c = colS[e];
        s_row[t] = r;
        s_col[t] = c;
        const float* pr = pos + ((size_t)b * NN + r) * 3;
        const float* pc = pos + ((size_t)b * NN + c) * 3;
        float dx = pr[0] - pc[0], dy = pr[1] - pc[1], dz = pr[2] - pc[2];
        s_ds[t] = dx * dx + dy * dy + dz * dz;
    }
    __syncthreads();

    const int ew = w * 32;
    const ushort* aptr[2][2];
    #pragma unroll
    for (int mt = 0; mt < 2; ++mt) {
        int el = ew + mt * 16 + l16;
        aptr[mt][0] = hb + ((size_t)b * NP + s_row[el]) * DD;
        aptr[mt][1] = hb + ((size_t)b * NP + s_col[el]) * DD;
    }
    float b1r[8], w1r[8], b2r[8];
    #pragma unroll
    for (int nt = 0; nt < 8; ++nt) {
        int d = nt * 16 + l16;
        b1r[nt] = b1[d]; w1r[nt] = w1last[d]; b2r[nt] = b2[d];
    }
    float dsr[2][4];
    #pragma unroll
    for (int mt = 0; mt < 2; ++mt)
        #pragma unroll
        for (int r = 0; r < 4; ++r) dsr[mt][r] = s_ds[ew + mt * 16 + quad * 4 + r];

    // GEMM1 (bias + dist_sq*w1last folded into acc init)
    floatx4 acc[2][8];
    #pragma unroll
    for (int mt = 0; mt < 2; ++mt)
        #pragma unroll
        for (int nt = 0; nt < 8; ++nt)
            #pragma unroll
            for (int r = 0; r < 4; ++r)
                acc[mt][nt][r] = b1r[nt] + dsr[mt][r] * w1r[nt];

    const short8* w1v = (const short8*)w1f;
    #pragma unroll
    for (int ks = 0; ks < 8; ++ks) {
        short8 bf[8];
        #pragma unroll
        for (int nt = 0; nt < 8; ++nt) bf[nt] = w1v[(ks * 8 + nt) * 64 + lane];
        const int half = ks >> 2;
        const int koff = (ks & 3) * 32 + quad * 8;
        #pragma unroll
        for (int mt = 0; mt < 2; ++mt) {
            short8 af = *(const short8*)(aptr[mt][half] + koff);
            #pragma unroll
            for (int nt = 0; nt < 8; ++nt)
                acc[mt][nt] = __builtin_amdgcn_mfma_f32_16x16x32_bf16(af, bf[nt], acc[mt][nt], 0, 0, 0);
        }
    }

    // lrelu -> s_mid (bf16, wave-private rows)
    #pragma unroll
    for (int mt = 0; mt < 2; ++mt)
        #pragma unroll
        for (int nt = 0; nt < 8; ++nt)
            #pragma unroll
            for (int r = 0; r < 4; ++r)
                s_buf[(ew + mt * 16 + quad * 4 + r) * MSTR + nt * 16 + l16] =
                    f2bf(lrelu(acc[mt][nt][r]));

    // GEMM2
    floatx4 acc2[2][8];
    #pragma unroll
    for (int mt = 0; mt < 2; ++mt)
        #pragma unroll
        for (int nt = 0; nt < 8; ++nt)
            #pragma unroll
            for (int r = 0; r < 4; ++r) acc2[mt][nt][r] = b2r[nt];

    const short8* w2v = (const short8*)w2f;
    #pragma unroll
    for (int ks = 0; ks < 4; ++ks) {
        short8 bf[8];
        #pragma unroll
        for (int nt = 0; nt < 8; ++nt) bf[nt] = w2v[(ks * 8 + nt) * 64 + lane];
        const int koff = ks * 32 + quad * 8;
        #pragma unroll
        for (int mt = 0; mt < 2; ++mt) {
            short8 af = *(const short8*)(&s_buf[(ew + mt * 16 + l16) * MSTR + koff]);
            #pragma unroll
            for (int nt = 0; nt < 8; ++nt)
                acc2[mt][nt] = __builtin_amdgcn_mfma_f32_16x16x32_bf16(af, bf[nt], acc2[mt][nt], 0, 0, 0);
        }
    }

    // segmented reduction over sorted cols, two 64-col passes through LDS fp32
    float* s_red = (float*)s_buf;
    #pragma unroll
    for (int ph = 0; ph < 2; ++ph) {
        __syncthreads();   // all waves done with s_buf's previous contents
        #pragma unroll
        for (int mt = 0; mt < 2; ++mt)
            #pragma unroll
            for (int nt4 = 0; nt4 < 4; ++nt4)
                #pragma unroll
                for (int r = 0; r < 4; ++r)
                    s_red[(ew + mt * 16 + quad * 4 + r) * RSTR + nt4 * 16 + l16] =
                        lrelu(acc2[mt][ph * 4 + nt4][r]);
        __syncthreads();
        // wave w scans its own 32 sorted rows; branches are wave-uniform
        const int r0 = w * 32;
        const int d  = ph * 64 + lane;
        float run = 0.0f;
        int prev = s_col[r0];
        for (int r = 0; r < 32; ++r) {
            int cid = s_col[r0 + r];
            float v = s_red[(r0 + r) * RSTR + lane];
            if (cid != prev) {
                atomicAdd(&aggr[((size_t)b * NP + prev) * DD + d], run);
                run = 0.0f;
                prev = cid;
            }
            run += v;
        }
        atomicAdd(&aggr[((size_t)b * NP + prev) * DD + d], run);
    }
}

// aggr -> aggr_mean (bf16) + coord/pos update
__global__ void k_aggr(const float* __restrict__ aggr, const float* __restrict__ cnt,
                       const float* __restrict__ cw, const float* __restrict__ cb,
                       float* __restrict__ pos, ushort* __restrict__ amb) {
    int b = blockIdx.y;
    int w = threadIdx.x >> 6, lane = threadIdx.x & 63;
    int n = blockIdx.x * 4 + w;
    if (n >= NN) return;
    float dn = cnt[n];
    dn = dn > 1.0f ? dn : 1.0f;
    float inv = 1.0f / dn;
    size_t base = ((size_t)b * NP + n) * DD;
    float a0 = aggr[base + lane] * inv;
    float a1 = aggr[base + 64 + lane] * inv;
    amb[base + lane] = f2bf(a0);
    amb[base + 64 + lane] = f2bf(a1);
    float p = a0 * cw[lane] + a1 * cw[64 + lane];
    #pragma unroll
    for (int off = 32; off > 0; off >>= 1) p += __shfl_down(p, off);
    if (lane == 0) {
        float cu = 0.1f * tanhf(p + cb[0]);
        float* pp = pos + ((size_t)b * NN + n) * 3;
        pp[0] += cu; pp[1] += cu; pp[2] += cu;
    }
}

// ---------------- node MLP (bf16 MFMA) + residual ----------------
__global__ __launch_bounds__(256) void k_node(
    ushort* hb, const ushort* __restrict__ amb,
    const ushort* __restrict__ w1f, const float* __restrict__ b1,
    const ushort* __restrict__ w2f, const float* __restrict__ b2,
    float* h)
{
    __shared__ __align__(16) ushort s_mid[128 * MSTR];

    const int b    = blockIdx.y;
    const int n0   = blockIdx.x * 128;
    const int t    = threadIdx.x;
    const int w    = t >> 6, lane = t & 63;
    const int quad = lane >> 4, l16 = lane & 15;
    const int ew   = w * 32;

    const ushort* aptr[2][2];
    #pragma unroll
    for (int mt = 0; mt < 2; ++mt) {
        size_t base = ((size_t)b * NP + n0 + ew + mt * 16 + l16) * DD;
        aptr[mt][0] = hb + base;
        aptr[mt][1] = amb + base;
    }
    float b1r[8], b2r[8];
    #pragma unroll
    for (int nt = 0; nt < 8; ++nt) {
        int d = nt * 16 + l16;
        b1r[nt] = b1[d]; b2r[nt] = b2[d];
    }

    floatx4 acc[2][8];
    #pragma unroll
    for (int mt = 0; mt < 2; ++mt)
        #pragma unroll
        for (int nt = 0; nt < 8; ++nt)
            #pragma unroll
            for (int r = 0; r < 4; ++r) acc[mt][nt][r] = b1r[nt];

    const short8* w1v = (const short8*)w1f;
    #pragma unroll
    for (int ks = 0; ks < 8; ++ks) {
        short8 bf[8];
        #pragma unroll
        for (int nt = 0; nt < 8; ++nt) bf[nt] = w1v[(ks * 8 + nt) * 64 + lane];
        const int half = ks >> 2;
        const int koff = (ks & 3) * 32 + quad * 8;
        #pragma unroll
        for (int mt = 0; mt < 2; ++mt) {
            short8 af = *(const short8*)(aptr[mt][half] + koff);
            #pragma unroll
            for (int nt = 0; nt < 8; ++nt)
                acc[mt][nt] = __builtin_amdgcn_mfma_f32_16x16x32_bf16(af, bf[nt], acc[mt][nt], 0, 0, 0);
        }
    }

    #pragma unroll
    for (int mt = 0; mt < 2; ++mt)
        #pragma unroll
        for (int nt = 0; nt < 8; ++nt)
            #pragma unroll
            for (int r = 0; r < 4; ++r)
                s_mid[(ew + mt * 16 + quad * 4 + r) * MSTR + nt * 16 + l16] =
                    f2bf(lrelu(acc[mt][nt][r]));

    floatx4 acc2[2][8];
    #pragma unroll
    for (int mt = 0; mt < 2; ++mt)
        #pragma unroll
        for (int nt = 0; nt < 8; ++nt)
            #pragma unroll
            for (int r = 0; r < 4; ++r) acc2[mt][nt][r] = b2r[nt];

    const short8* w2v = (const short8*)w2f;
    #pragma unroll
    for (int ks = 0; ks < 4; ++ks) {
        short8 bf[8];
        #pragma unroll
        for (int nt = 0; nt < 8; ++nt) bf[nt] = w2v[(ks * 8 + nt) * 64 + lane];
        const int koff = ks * 32 + quad * 8;
        #pragma unroll
        for (int mt = 0; mt < 2; ++mt) {
            short8 af = *(const short8*)(&s_mid[(ew + mt * 16 + l16) * MSTR + koff]);
            #pragma unroll
            for (int nt = 0; nt < 8; ++nt)
                acc2[mt][nt] = __builtin_amdgcn_mfma_f32_16x16x32_bf16(af, bf[nt], acc2[mt][nt], 0, 0, 0);
        }
    }

    #pragma unroll
    for (int mt = 0; mt < 2; ++mt)
        #pragma unroll
        for (int r = 0; r < 4; ++r) {
            int n = n0 + ew + mt * 16 + quad * 4 + r;
            if (n < NN) {
                size_t base = ((size_t)b * NP + n) * DD;
                #pragma unroll
                for (int nt = 0; nt < 8; ++nt) {
                    int d = nt * 16 + l16;
                    float hv = h[base + d] + lrelu(acc2[mt][nt][r]);
                    h[base + d] = hv;
                    hb[base + d] = f2bf(hv);
                }
            }
        }
}

#define NPC 50
__global__ void k_mean(const float* __restrict__ h, float* __restrict__ hm) {
    int b  = blockIdx.y;
    int n0 = blockIdx.x * NPC;
    int d  = threadIdx.x;
    float s = 0.0f;
    for (int n = n0; n < n0 + NPC; ++n) s += h[((size_t)b * NP + n) * DD + d];
    atomicAdd(&hm[b * DD + d], s);
}

__global__ void k_proj(const float* __restrict__ hm, const float* __restrict__ wp,
                       const float* __restrict__ bp, float* __restrict__ out) {
    int t = threadIdx.x;
    int b = t >> 6, o = t & (OUTD - 1);
    float s = 0.0f;
    for (int d2 = 0; d2 < DD; ++d2) s += hm[b * DD + d2] * wp[d2 * OUTD + o];
    s = s * (1.0f / NN) + bp[o];
    out[b * OUTD + o] = lrelu(s);
}

extern "C" void kernel_launch(void* const* d_in, const int* in_sizes, int n_in,
                              void* d_out, int out_size, void* d_ws, size_t ws_size,
                              hipStream_t stream) {
    (void)in_sizes; (void)n_in; (void)out_size; (void)ws_size;
    const float* x   = (const float*)d_in[0];
    const int*   ei  = (const int*)d_in[1];
    const float* w0  = (const float*)d_in[2];
    const float* b0  = (const float*)d_in[3];
    const float* ew1 = (const float*)d_in[4];
    const float* eb1 = (const float*)d_in[5];
    const float* ew2 = (const float*)d_in[6];
    const float* eb2 = (const float*)d_in[7];
    const float* cw  = (const float*)d_in[8];
    const float* cb  = (const float*)d_in[9];
    const float* nw1 = (const float*)d_in[10];
    const float* nb1 = (const float*)d_in[11];
    const float* nw2 = (const float*)d_in[12];
    const float* nb2 = (const float*)d_in[13];
    const float* wp  = (const float*)d_in[14];
    const float* bp  = (const float*)d_in[15];
    const int* row = ei;
    const int* col = ei + EE;

    const size_t HSZ = (size_t)BB * NP * DD;
    float* ws   = (float*)d_ws;
    float* h    = ws;
    float* aggr = h + HSZ;
    float* pos  = aggr + HSZ;
    float* cnt  = pos + (size_t)BB * NN * 3;
    float* hm   = cnt + NN;
    ushort* hb   = (ushort*)(hm + 512);
    ushort* amb  = hb + HSZ;
    ushort* ew1f = amb + HSZ;
    ushort* ew2f = ew1f + (size_t)LL * 32768;
    ushort* nw1f = ew2f + (size_t)LL * 16384;
    ushort* nw2f = nw1f + (size_t)LL * 32768;
    int* ecnt   = (int*)(nw2f + (size_t)LL * 16384);
    int* cursor = ecnt + NN;
    int* rowS   = cursor + NN;
    int* colS   = rowS + EE;

    hipMemcpyAsync(pos, x, sizeof(float) * (size_t)BB * NN * 3,
                   hipMemcpyDeviceToDevice, stream);
    hipMemsetAsync(cnt, 0, sizeof(float) * NN, stream);
    hipMemsetAsync(ecnt, 0, sizeof(int) * NN, stream);
    hipMemsetAsync(hm, 0, sizeof(float) * BB * DD, stream);

    k_cvtw<<<(LL * 8 * 512 + 255) / 256, 256, 0, stream>>>(ew1, ew1f, 257, 8);
    k_cvtw<<<(LL * 4 * 512 + 255) / 256, 256, 0, stream>>>(ew2, ew2f, 128, 4);
    k_cvtw<<<(LL * 8 * 512 + 255) / 256, 256, 0, stream>>>(nw1, nw1f, 256, 8);
    k_cvtw<<<(LL * 4 * 512 + 255) / 256, 256, 0, stream>>>(nw2, nw2f, 128, 4);

    k_h0<<<((int)HSZ + 255) / 256, 256, 0, stream>>>(x, w0, b0, h, hb);
    k_count<<<(EE + 255) / 256, 256, 0, stream>>>(col, cnt, ecnt);
    k_scan<<<1, 256, 0, stream>>>(ecnt, cursor);
    k_place<<<(EE + 255) / 256, 256, 0, stream>>>(row, col, cursor, rowS, colS);

    for (int i = 0; i < LL; ++i) {
        hipMemsetAsync(aggr, 0, sizeof(float) * HSZ, stream);
        k_edge<<<dim3(EE / 128, BB), 256, 0, stream>>>(
            pos, hb, rowS, colS,
            ew1f + (size_t)i * 32768,
            ew1 + (size_t)i * 257 * DD + (size_t)256 * DD,
            eb1 + (size_t)i * DD,
            ew2f + (size_t)i * 16384,
            eb2 + (size_t)i * DD,
            aggr);
        k_aggr<<<dim3((NN + 3) / 4, BB), 256, 0, stream>>>(
            aggr, cnt, cw + (size_t)i * DD, cb + i, pos, amb);
        k_node<<<dim3(NP / 128, BB), 256, 0, stream>>>(
            hb, amb,
            nw1f + (size_t)i * 32768, nb1 + (size_t)i * DD,
            nw2f + (size_t)i * 16384, nb2 + (size_t)i * DD,
            h);
    }

    k_mean<<<dim3(NN / NPC, BB), DD, 0, stream>>>(h, hm);
    k_proj<<<1, 256, 0, stream>>>(hm, wp, bp, (float*)d_out);
}

// Round 4
// 780.633 us; speedup vs baseline: 7.8663x; 1.1549x over previous
//
#include <hip/hip_runtime.h>
#include <hip/hip_bf16.h>
#include <math.h>

#define BB   4
#define NN   10000
#define NP   10112          // NN padded to multiple of 128
#define EE   160000         // = 1250 * 128
#define DD   128
#define OUTD 64
#define LL   4
#define NEGS 0.01f
#define MSTR 136            // k_node s_mid row stride (bf16 elems)
#define RSTRF 68            // k_edge s_red row stride (fp32): bank=(4*row+col)&31 -> 2-way max

typedef __attribute__((ext_vector_type(8))) short   short8;
typedef __attribute__((ext_vector_type(4))) float   floatx4;

__device__ __forceinline__ float lrelu(float x) { return fmaxf(x, NEGS * x); }
__device__ __forceinline__ ushort f2bf(float x) {
    __hip_bfloat16 b = __float2bfloat16(x);
    return *reinterpret_cast<ushort*>(&b);
}
__device__ __forceinline__ float bf2f(ushort u) {
    uint v = ((uint)u) << 16;
    return *reinterpret_cast<float*>(&v);
}

// ---- weights -> MFMA B-fragment layout: dst[l][ks][nt][lane][j] = W[l][ks*32+quad*8+j][nt*16+l16]
__global__ void k_cvtw(const float* __restrict__ src, ushort* __restrict__ dst,
                       int rowpitch, int nks) {
    int tid = blockIdx.x * 256 + threadIdx.x;
    if (tid >= LL * nks * 512) return;
    int lane = tid & 63;
    int nt   = (tid >> 6) & 7;
    int ks   = (tid >> 9) % nks;
    int l    = tid / (nks * 512);
    int quad = lane >> 4, l16 = lane & 15;
    int n = nt * 16 + l16;
    const float* s = src + (size_t)l * rowpitch * DD;
    ushort* d = dst + (size_t)tid * 8;
    #pragma unroll
    for (int j = 0; j < 8; ++j)
        d[j] = f2bf(s[(size_t)(ks * 32 + quad * 8 + j) * DD + n]);
}

__global__ void k_h0(const float* __restrict__ x, const float* __restrict__ w0,
                     const float* __restrict__ b0, float* __restrict__ h,
                     ushort* __restrict__ hb) {
    int idx = blockIdx.x * 256 + threadIdx.x;
    if (idx >= BB * NP * DD) return;
    int d  = idx & (DD - 1);
    int bn = idx >> 7;
    int n  = bn % NP, b = bn / NP;
    float v = 0.0f;
    if (n < NN) {
        const float* p = x + ((size_t)b * NN + n) * 3;
        v = lrelu(b0[d] + p[0] * w0[d] + p[1] * w0[DD + d] + p[2] * w0[2 * DD + d]);
    }
    h[idx] = v;
    hb[idx] = f2bf(v);
}

__global__ void k_count(const int* __restrict__ col, float* __restrict__ cnt,
                        int* __restrict__ ecnt) {
    int e = blockIdx.x * blockDim.x + threadIdx.x;
    if (e < EE) {
        int c = col[e];
        atomicAdd(&cnt[c], 1.0f);
        atomicAdd(&ecnt[c], 1);
    }
}

__global__ __launch_bounds__(256) void k_scan(const int* __restrict__ ecnt,
                                              int* __restrict__ cursor) {
    __shared__ int s_sum[256];
    int t = threadIdx.x;
    int base = t * 40;
    int s = 0;
    for (int i = 0; i < 40; ++i) {
        int n = base + i;
        if (n < NN) s += ecnt[n];
    }
    s_sum[t] = s;
    __syncthreads();
    if (t == 0) {
        int a = 0;
        for (int i = 0; i < 256; ++i) { int v = s_sum[i]; s_sum[i] = a; a += v; }
    }
    __syncthreads();
    int a = s_sum[t];
    for (int i = 0; i < 40; ++i) {
        int n = base + i;
        if (n < NN) { cursor[n] = a; a += ecnt[n]; }
    }
}

__global__ void k_place(const int* __restrict__ row, const int* __restrict__ col,
                        int* __restrict__ cursor,
                        int* __restrict__ rowS, int* __restrict__ colS) {
    int e = blockIdx.x * blockDim.x + threadIdx.x;
    if (e >= EE) return;
    int c = col[e];
    int p = atomicAdd(&cursor[c], 1);
    rowS[p] = row[e];
    colS[p] = c;
}

// ---------------- P/Q node GEMMs: P = h@W_top, Q = h@W_mid + b1 ----------------
__global__ __launch_bounds__(256) void k_pq(
    const ushort* __restrict__ hb, const ushort* __restrict__ wtf,
    const ushort* __restrict__ wmf, const float* __restrict__ b1,
    ushort* __restrict__ P, ushort* __restrict__ Q)
{
    const int b = blockIdx.y, n0 = blockIdx.x * 128, t = threadIdx.x;
    const int w = t >> 6, lane = t & 63, quad = lane >> 4, l16 = lane & 15;
    const int ew = w * 32;

    const ushort* aptr[2];
    #pragma unroll
    for (int mt = 0; mt < 2; ++mt)
        aptr[mt] = hb + ((size_t)b * NP + n0 + ew + mt * 16 + l16) * DD;

    float b1r[8];
    #pragma unroll
    for (int nt = 0; nt < 8; ++nt) b1r[nt] = b1[nt * 16 + l16];

    floatx4 accP[2][8], accQ[2][8];
    #pragma unroll
    for (int mt = 0; mt < 2; ++mt)
        #pragma unroll
        for (int nt = 0; nt < 8; ++nt)
            #pragma unroll
            for (int r = 0; r < 4; ++r) { accP[mt][nt][r] = 0.0f; accQ[mt][nt][r] = b1r[nt]; }

    const short8* wt = (const short8*)wtf;
    const short8* wm = (const short8*)wmf;
    #pragma unroll
    for (int ks = 0; ks < 4; ++ks) {
        short8 bt[8], bm[8];
        #pragma unroll
        for (int nt = 0; nt < 8; ++nt) {
            bt[nt] = wt[(ks * 8 + nt) * 64 + lane];
            bm[nt] = wm[(ks * 8 + nt) * 64 + lane];
        }
        const int koff = ks * 32 + quad * 8;
        #pragma unroll
        for (int mt = 0; mt < 2; ++mt) {
            short8 af = *(const short8*)(aptr[mt] + koff);
            #pragma unroll
            for (int nt = 0; nt < 8; ++nt) {
                accP[mt][nt] = __builtin_amdgcn_mfma_f32_16x16x32_bf16(af, bt[nt], accP[mt][nt], 0, 0, 0);
                accQ[mt][nt] = __builtin_amdgcn_mfma_f32_16x16x32_bf16(af, bm[nt], accQ[mt][nt], 0, 0, 0);
            }
        }
    }

    #pragma unroll
    for (int mt = 0; mt < 2; ++mt)
        #pragma unroll
        for (int r = 0; r < 4; ++r) {
            int n = n0 + ew + mt * 16 + quad * 4 + r;
            size_t base = ((size_t)b * NP + n) * DD + l16;
            #pragma unroll
            for (int nt = 0; nt < 8; ++nt) {
                P[base + nt * 16] = f2bf(accP[mt][nt][r]);
                Q[base + nt * 16] = f2bf(accQ[mt][nt][r]);
            }
        }
}

// ---------------- edge kernel: mid = lrelu(P[row]+Q[col]+ds*w1last), GEMM2, seg-reduce ----------------
// 1D grid 5000 blocks; XCD-pair affinity: batch = (g>>1)&3
__global__ __launch_bounds__(256) void k_edge(
    const float* __restrict__ pos,
    const ushort* __restrict__ P, const ushort* __restrict__ Q,
    const int* __restrict__ rowS, const int* __restrict__ colS,
    const float* __restrict__ w1last,
    const ushort* __restrict__ w2f, const float* __restrict__ b2,
    float* __restrict__ aggr)
{
    __shared__ int   s_row[128];
    __shared__ int   s_col[128];
    __shared__ float s_ds[128];
    __shared__ float s_red[128 * RSTRF];

    const int g    = blockIdx.x;
    const int b    = (g >> 1) & 3;
    const int tile = (g >> 3) * 2 + (g & 1);
    const int e0   = tile * 128;
    const int t    = threadIdx.x;
    const int w    = t >> 6, lane = t & 63;
    const int quad = lane >> 4, l16 = lane & 15;

    if (t < 128) {
        int e = e0 + t;
        int r = rowS[e], c = colS[e];
        s_row[t] = r;
        s_col[t] = c;
        const float* pr = pos + ((size_t)b * NN + r) * 3;
        const float* pc = pos + ((size_t)b * NN + c) * 3;
        float dx = pr[0] - pc[0], dy = pr[1] - pc[1], dz = pr[2] - pc[2];
        s_ds[t] = dx * dx + dy * dy + dz * dz;
    }
    __syncthreads();

    const int ew = w * 32;
    const ushort* pptr[2];
    const ushort* qptr[2];
    float dsv[2];
    #pragma unroll
    for (int mt = 0; mt < 2; ++mt) {
        int el = ew + mt * 16 + l16;
        pptr[mt] = P + ((size_t)b * NP + s_row[el]) * DD;
        qptr[mt] = Q + ((size_t)b * NP + s_col[el]) * DD;
        dsv[mt]  = s_ds[el];
    }
    float b2r[8];
    #pragma unroll
    for (int nt = 0; nt < 8; ++nt) b2r[nt] = b2[nt * 16 + l16];

    floatx4 acc2[2][8];
    #pragma unroll
    for (int mt = 0; mt < 2; ++mt)
        #pragma unroll
        for (int nt = 0; nt < 8; ++nt)
            #pragma unroll
            for (int r = 0; r < 4; ++r) acc2[mt][nt][r] = b2r[nt];

    const short8* w2v = (const short8*)w2f;
    #pragma unroll
    for (int ks = 0; ks < 4; ++ks) {
        const int koff = ks * 32 + quad * 8;
        floatx4 wl0 = *(const floatx4*)(w1last + koff);
        floatx4 wl1 = *(const floatx4*)(w1last + koff + 4);
        short8 bf[8];
        #pragma unroll
        for (int nt = 0; nt < 8; ++nt) bf[nt] = w2v[(ks * 8 + nt) * 64 + lane];
        #pragma unroll
        for (int mt = 0; mt < 2; ++mt) {
            short8 pr = *(const short8*)(pptr[mt] + koff);
            short8 qr = *(const short8*)(qptr[mt] + koff);
            short8 af;
            #pragma unroll
            for (int j = 0; j < 4; ++j) {
                float v = bf2f((ushort)pr[j]) + bf2f((ushort)qr[j]) + dsv[mt] * wl0[j];
                af[j] = f2bf(lrelu(v));
            }
            #pragma unroll
            for (int j = 0; j < 4; ++j) {
                float v = bf2f((ushort)pr[4 + j]) + bf2f((ushort)qr[4 + j]) + dsv[mt] * wl1[j];
                af[4 + j] = f2bf(lrelu(v));
            }
            #pragma unroll
            for (int nt = 0; nt < 8; ++nt)
                acc2[mt][nt] = __builtin_amdgcn_mfma_f32_16x16x32_bf16(af, bf[nt], acc2[mt][nt], 0, 0, 0);
        }
    }

    // segmented reduction over sorted cols; rows [ew, ew+32) are wave-private -> no barriers
    #pragma unroll
    for (int ph = 0; ph < 2; ++ph) {
        #pragma unroll
        for (int mt = 0; mt < 2; ++mt)
            #pragma unroll
            for (int ntl = 0; ntl < 4; ++ntl)
                #pragma unroll
                for (int r = 0; r < 4; ++r)
                    s_red[(ew + mt * 16 + quad * 4 + r) * RSTRF + ntl * 16 + l16] =
                        lrelu(acc2[mt][ph * 4 + ntl][r]);
        const int d = ph * 64 + lane;
        float run = 0.0f;
        int prev = s_col[ew];
        for (int r = 0; r < 32; ++r) {
            int cid = s_col[ew + r];
            float v = s_red[(ew + r) * RSTRF + lane];
            if (cid != prev) {
                atomicAdd(&aggr[((size_t)b * NP + prev) * DD + d], run);
                run = 0.0f;
                prev = cid;
            }
            run += v;
        }
        atomicAdd(&aggr[((size_t)b * NP + prev) * DD + d], run);
    }
}

// ---------------- node MLP (fused aggr-mean + coord/pos update + residual) ----------------
__global__ __launch_bounds__(256) void k_node(
    ushort* hb, const float* __restrict__ aggr, const float* __restrict__ cnt,
    const float* __restrict__ cw, const float* __restrict__ cb,
    const ushort* __restrict__ w1f, const float* __restrict__ b1,
    const ushort* __restrict__ w2f, const float* __restrict__ b2,
    float* h, float* __restrict__ pos)
{
    __shared__ __align__(16) ushort s_mid[128 * MSTR];

    const int b    = blockIdx.y;
    const int n0   = blockIdx.x * 128;
    const int t    = threadIdx.x;
    const int w    = t >> 6, lane = t & 63;
    const int quad = lane >> 4, l16 = lane & 15;
    const int ew   = w * 32;

    const ushort* hptr[2];
    const float*  aptr[2];
    float inv[2];
    #pragma unroll
    for (int mt = 0; mt < 2; ++mt) {
        int node = n0 + ew + mt * 16 + l16;
        size_t base = ((size_t)b * NP + node) * DD;
        hptr[mt] = hb + base;
        aptr[mt] = aggr + base;
        float dn = 1.0f;
        if (node < NN) { dn = cnt[node]; dn = dn > 1.0f ? dn : 1.0f; inv[mt] = 1.0f / dn; }
        else inv[mt] = 0.0f;
    }
    float b1r[8], b2r[8];
    #pragma unroll
    for (int nt = 0; nt < 8; ++nt) {
        int d = nt * 16 + l16;
        b1r[nt] = b1[d]; b2r[nt] = b2[d];
    }

    floatx4 acc[2][8];
    #pragma unroll
    for (int mt = 0; mt < 2; ++mt)
        #pragma unroll
        for (int nt = 0; nt < 8; ++nt)
            #pragma unroll
            for (int r = 0; r < 4; ++r) acc[mt][nt][r] = b1r[nt];

    float cwacc[2] = {0.0f, 0.0f};
    const short8* w1v = (const short8*)w1f;
    #pragma unroll
    for (int ks = 0; ks < 8; ++ks) {
        short8 bf[8];
        #pragma unroll
        for (int nt = 0; nt < 8; ++nt) bf[nt] = w1v[(ks * 8 + nt) * 64 + lane];
        const int koff = (ks & 3) * 32 + quad * 8;
        if (ks < 4) {
            #pragma unroll
            for (int mt = 0; mt < 2; ++mt) {
                short8 af = *(const short8*)(hptr[mt] + koff);
                #pragma unroll
                for (int nt = 0; nt < 8; ++nt)
                    acc[mt][nt] = __builtin_amdgcn_mfma_f32_16x16x32_bf16(af, bf[nt], acc[mt][nt], 0, 0, 0);
            }
        } else {
            floatx4 cw0 = *(const floatx4*)(cw + koff);
            floatx4 cw1 = *(const floatx4*)(cw + koff + 4);
            #pragma unroll
            for (int mt = 0; mt < 2; ++mt) {
                floatx4 a0 = *(const floatx4*)(aptr[mt] + koff);
                floatx4 a1 = *(const floatx4*)(aptr[mt] + koff + 4);
                short8 af;
                #pragma unroll
                for (int j = 0; j < 4; ++j) {
                    float v = a0[j] * inv[mt];
                    af[j] = f2bf(v);
                    cwacc[mt] += v * cw0[j];
                }
                #pragma unroll
                for (int j = 0; j < 4; ++j) {
                    float v = a1[j] * inv[mt];
                    af[4 + j] = f2bf(v);
                    cwacc[mt] += v * cw1[j];
                }
                #pragma unroll
                for (int nt = 0; nt < 8; ++nt)
                    acc[mt][nt] = __builtin_amdgcn_mfma_f32_16x16x32_bf16(af, bf[nt], acc[mt][nt], 0, 0, 0);
            }
        }
    }

    // coord update: reduce cw-dot across quads (lanes l16, l16+16, l16+32, l16+48)
    float cb0 = cb[0];
    #pragma unroll
    for (int mt = 0; mt < 2; ++mt) {
        float full = cwacc[mt];
        full += __shfl_xor(full, 16);
        full += __shfl_xor(full, 32);
        int node = n0 + ew + mt * 16 + l16;
        if (quad == 0 && node < NN) {
            float cu = 0.1f * tanhf(full + cb0);
            float* pp = pos + ((size_t)b * NN + node) * 3;
            pp[0] += cu; pp[1] += cu; pp[2] += cu;
        }
    }

    #pragma unroll
    for (int mt = 0; mt < 2; ++mt)
        #pragma unroll
        for (int nt = 0; nt < 8; ++nt)
            #pragma unroll
            for (int r = 0; r < 4; ++r)
                s_mid[(ew + mt * 16 + quad * 4 + r) * MSTR + nt * 16 + l16] =
                    f2bf(lrelu(acc[mt][nt][r]));

    floatx4 acc2[2][8];
    #pragma unroll
    for (int mt = 0; mt < 2; ++mt)
        #pragma unroll
        for (int nt = 0; nt < 8; ++nt)
            #pragma unroll
            for (int r = 0; r < 4; ++r) acc2[mt][nt][r] = b2r[nt];

    const short8* w2v = (const short8*)w2f;
    #pragma unroll
    for (int ks = 0; ks < 4; ++ks) {
        short8 bf[8];
        #pragma unroll
        for (int nt = 0; nt < 8; ++nt) bf[nt] = w2v[(ks * 8 + nt) * 64 + lane];
        const int koff = ks * 32 + quad * 8;
        #pragma unroll
        for (int mt = 0; mt < 2; ++mt) {
            short8 af = *(const short8*)(&s_mid[(ew + mt * 16 + l16) * MSTR + koff]);
            #pragma unroll
            for (int nt = 0; nt < 8; ++nt)
                acc2[mt][nt] = __builtin_amdgcn_mfma_f32_16x16x32_bf16(af, bf[nt], acc2[mt][nt], 0, 0, 0);
        }
    }

    #pragma unroll
    for (int mt = 0; mt < 2; ++mt)
        #pragma unroll
        for (int r = 0; r < 4; ++r) {
            int n = n0 + ew + mt * 16 + quad * 4 + r;
            if (n < NN) {
                size_t base = ((size_t)b * NP + n) * DD;
                #pragma unroll
                for (int nt = 0; nt < 8; ++nt) {
                    int d = nt * 16 + l16;
                    float hv = h[base + d] + lrelu(acc2[mt][nt][r]);
                    h[base + d] = hv;
                    hb[base + d] = f2bf(hv);
                }
            }
        }
}

#define NPC 50
__global__ void k_mean(const float* __restrict__ h, float* __restrict__ hm) {
    int b  = blockIdx.y;
    int n0 = blockIdx.x * NPC;
    int d  = threadIdx.x;
    float s = 0.0f;
    for (int n = n0; n < n0 + NPC; ++n) s += h[((size_t)b * NP + n) * DD + d];
    atomicAdd(&hm[b * DD + d], s);
}

__global__ void k_proj(const float* __restrict__ hm, const float* __restrict__ wp,
                       const float* __restrict__ bp, float* __restrict__ out) {
    int t = threadIdx.x;
    int b = t >> 6, o = t & (OUTD - 1);
    float s = 0.0f;
    for (int d2 = 0; d2 < DD; ++d2) s += hm[b * DD + d2] * wp[d2 * OUTD + o];
    s = s * (1.0f / NN) + bp[o];
    out[b * OUTD + o] = lrelu(s);
}

extern "C" void kernel_launch(void* const* d_in, const int* in_sizes, int n_in,
                              void* d_out, int out_size, void* d_ws, size_t ws_size,
                              hipStream_t stream) {
    (void)in_sizes; (void)n_in; (void)out_size; (void)ws_size;
    const float* x   = (const float*)d_in[0];
    const int*   ei  = (const int*)d_in[1];
    const float* w0  = (const float*)d_in[2];
    const float* b0  = (const float*)d_in[3];
    const float* ew1 = (const float*)d_in[4];
    const float* eb1 = (const float*)d_in[5];
    const float* ew2 = (const float*)d_in[6];
    const float* eb2 = (const float*)d_in[7];
    const float* cw  = (const float*)d_in[8];
    const float* cb  = (const float*)d_in[9];
    const float* nw1 = (const float*)d_in[10];
    const float* nb1 = (const float*)d_in[11];
    const float* nw2 = (const float*)d_in[12];
    const float* nb2 = (const float*)d_in[13];
    const float* wp  = (const float*)d_in[14];
    const float* bp  = (const float*)d_in[15];
    const int* row = ei;
    const int* col = ei + EE;

    const size_t HSZ = (size_t)BB * NP * DD;
    float* ws   = (float*)d_ws;
    float* h    = ws;
    float* aggr = h + HSZ;
    float* pos  = aggr + HSZ;
    float* cnt  = pos + (size_t)BB * NN * 3;
    float* hm   = cnt + NN;
    ushort* hb    = (ushort*)(hm + 512);
    ushort* Pb    = hb + HSZ;
    ushort* Qb    = Pb + HSZ;
    ushort* wtopf = Qb + HSZ;                           // LL*16384
    ushort* wmidf = wtopf + (size_t)LL * 16384;
    ushort* ew2f  = wmidf + (size_t)LL * 16384;
    ushort* nw1f  = ew2f + (size_t)LL * 16384;          // LL*32768
    ushort* nw2f  = nw1f + (size_t)LL * 32768;
    int* ecnt   = (int*)(nw2f + (size_t)LL * 16384);
    int* cursor = ecnt + NN;
    int* rowS   = cursor + NN;
    int* colS   = rowS + EE;

    hipMemcpyAsync(pos, x, sizeof(float) * (size_t)BB * NN * 3,
                   hipMemcpyDeviceToDevice, stream);
    hipMemsetAsync(cnt, 0, sizeof(float) * NN, stream);
    hipMemsetAsync(ecnt, 0, sizeof(int) * NN, stream);
    hipMemsetAsync(hm, 0, sizeof(float) * BB * DD, stream);

    k_cvtw<<<(LL * 4 * 512 + 255) / 256, 256, 0, stream>>>(ew1, wtopf, 257, 4);
    k_cvtw<<<(LL * 4 * 512 + 255) / 256, 256, 0, stream>>>(ew1 + (size_t)128 * DD, wmidf, 257, 4);
    k_cvtw<<<(LL * 4 * 512 + 255) / 256, 256, 0, stream>>>(ew2, ew2f, 128, 4);
    k_cvtw<<<(LL * 8 * 512 + 255) / 256, 256, 0, stream>>>(nw1, nw1f, 256, 8);
    k_cvtw<<<(LL * 4 * 512 + 255) / 256, 256, 0, stream>>>(nw2, nw2f, 128, 4);

    k_h0<<<((int)HSZ + 255) / 256, 256, 0, stream>>>(x, w0, b0, h, hb);
    k_count<<<(EE + 255) / 256, 256, 0, stream>>>(col, cnt, ecnt);
    k_scan<<<1, 256, 0, stream>>>(ecnt, cursor);
    k_place<<<(EE + 255) / 256, 256, 0, stream>>>(row, col, cursor, rowS, colS);

    k_pq<<<dim3(NP / 128, BB), 256, 0, stream>>>(
        hb, wtopf, wmidf, eb1, Pb, Qb);

    for (int i = 0; i < LL; ++i) {
        hipMemsetAsync(aggr, 0, sizeof(float) * HSZ, stream);
        k_edge<<<(EE / 128) * BB, 256, 0, stream>>>(
            pos, Pb, Qb, rowS, colS,
            ew1 + (size_t)i * 257 * DD + (size_t)256 * DD,
            ew2f + (size_t)i * 16384,
            eb2 + (size_t)i * DD,
            aggr);
        k_node<<<dim3(NP / 128, BB), 256, 0, stream>>>(
            hb, aggr, cnt,
            cw + (size_t)i * DD, cb + i,
            nw1f + (size_t)i * 32768, nb1 + (size_t)i * DD,
            nw2f + (size_t)i * 16384, nb2 + (size_t)i * DD,
            h, pos);
        if (i < LL - 1)
            k_pq<<<dim3(NP / 128, BB), 256, 0, stream>>>(
                hb, wtopf + (size_t)(i + 1) * 16384, wmidf + (size_t)(i + 1) * 16384,
                eb1 + (size_t)(i + 1) * DD, Pb, Qb);
    }

    k_mean<<<dim3(NN / NPC, BB), DD, 0, stream>>>(h, hm);
    k_proj<<<1, 256, 0, stream>>>(hm, wp, bp, (float*)d_out);
}

// Round 5
// 731.186 us; speedup vs baseline: 8.3982x; 1.0676x over previous
//
#include <hip/hip_runtime.h>
#include <hip/hip_bf16.h>
#include <math.h>

#define BB   4
#define NN   10000
#define NP   10112          // NN padded to multiple of 128
#define EE   160000         // = 1250 * 128
#define DD   128
#define OUTD 64
#define LL   4
#define NEGS 0.01f
#define MSTR 136            // k_node s_mid row stride (bf16 elems)
#define RSH  68             // k_edge s_red row stride (bf16): quad rows 8 banks apart -> conflict-free

typedef __attribute__((ext_vector_type(8))) short   short8;
typedef __attribute__((ext_vector_type(4))) float   floatx4;

__device__ __forceinline__ float lrelu(float x) { return fmaxf(x, NEGS * x); }
__device__ __forceinline__ ushort f2bf(float x) {
    __hip_bfloat16 b = __float2bfloat16(x);
    return *reinterpret_cast<ushort*>(&b);
}
__device__ __forceinline__ float bf2f(ushort u) {
    uint v = ((uint)u) << 16;
    return *reinterpret_cast<float*>(&v);
}

// ---- weights -> MFMA B-fragment layout: dst[l][ks][nt][lane][j] = W[l][ks*32+quad*8+j][nt*16+l16]
__global__ void k_cvtw(const float* __restrict__ src, ushort* __restrict__ dst,
                       int rowpitch, int nks) {
    int tid = blockIdx.x * 256 + threadIdx.x;
    if (tid >= LL * nks * 512) return;
    int lane = tid & 63;
    int nt   = (tid >> 6) & 7;
    int ks   = (tid >> 9) % nks;
    int l    = tid / (nks * 512);
    int quad = lane >> 4, l16 = lane & 15;
    int n = nt * 16 + l16;
    const float* s = src + (size_t)l * rowpitch * DD;
    ushort* d = dst + (size_t)tid * 8;
    #pragma unroll
    for (int j = 0; j < 8; ++j)
        d[j] = f2bf(s[(size_t)(ks * 32 + quad * 8 + j) * DD + n]);
}

__global__ void k_h0(const float* __restrict__ x, const float* __restrict__ w0,
                     const float* __restrict__ b0, float* __restrict__ h,
                     ushort* __restrict__ hb) {
    int idx = blockIdx.x * 256 + threadIdx.x;
    if (idx >= BB * NP * DD) return;
    int d  = idx & (DD - 1);
    int bn = idx >> 7;
    int n  = bn % NP, b = bn / NP;
    float v = 0.0f;
    if (n < NN) {
        const float* p = x + ((size_t)b * NN + n) * 3;
        v = lrelu(b0[d] + p[0] * w0[d] + p[1] * w0[DD + d] + p[2] * w0[2 * DD + d]);
    }
    h[idx] = v;
    hb[idx] = f2bf(v);
}

__global__ void k_count(const int* __restrict__ col, float* __restrict__ cnt,
                        int* __restrict__ ecnt) {
    int e = blockIdx.x * blockDim.x + threadIdx.x;
    if (e < EE) {
        int c = col[e];
        atomicAdd(&cnt[c], 1.0f);
        atomicAdd(&ecnt[c], 1);
    }
}

__global__ __launch_bounds__(256) void k_scan(const int* __restrict__ ecnt,
                                              int* __restrict__ cursor) {
    __shared__ int s_sum[256];
    int t = threadIdx.x;
    int base = t * 40;
    int s = 0;
    for (int i = 0; i < 40; ++i) {
        int n = base + i;
        if (n < NN) s += ecnt[n];
    }
    s_sum[t] = s;
    __syncthreads();
    if (t == 0) {
        int a = 0;
        for (int i = 0; i < 256; ++i) { int v = s_sum[i]; s_sum[i] = a; a += v; }
    }
    __syncthreads();
    int a = s_sum[t];
    for (int i = 0; i < 40; ++i) {
        int n = base + i;
        if (n < NN) { cursor[n] = a; a += ecnt[n]; }
    }
}

__global__ void k_place(const int* __restrict__ row, const int* __restrict__ col,
                        int* __restrict__ cursor,
                        int* __restrict__ rowS, int* __restrict__ colS) {
    int e = blockIdx.x * blockDim.x + threadIdx.x;
    if (e >= EE) return;
    int c = col[e];
    int p = atomicAdd(&cursor[c], 1);
    rowS[p] = row[e];
    colS[p] = c;
}

// ---------------- initial P/Q node GEMMs (layer 0): P = h@W_top, Q = h@W_mid + b1 ----------------
__global__ __launch_bounds__(256) void k_pq(
    const ushort* __restrict__ hb, const ushort* __restrict__ wtf,
    const ushort* __restrict__ wmf, const float* __restrict__ b1,
    ushort* __restrict__ P, ushort* __restrict__ Q)
{
    const int b = blockIdx.y, n0 = blockIdx.x * 128, t = threadIdx.x;
    const int w = t >> 6, lane = t & 63, quad = lane >> 4, l16 = lane & 15;
    const int ew = w * 32;

    const ushort* aptr[2];
    #pragma unroll
    for (int mt = 0; mt < 2; ++mt)
        aptr[mt] = hb + ((size_t)b * NP + n0 + ew + mt * 16 + l16) * DD;

    float b1r[8];
    #pragma unroll
    for (int nt = 0; nt < 8; ++nt) b1r[nt] = b1[nt * 16 + l16];

    floatx4 accP[2][8], accQ[2][8];
    #pragma unroll
    for (int mt = 0; mt < 2; ++mt)
        #pragma unroll
        for (int nt = 0; nt < 8; ++nt)
            #pragma unroll
            for (int r = 0; r < 4; ++r) { accP[mt][nt][r] = 0.0f; accQ[mt][nt][r] = b1r[nt]; }

    const short8* wt = (const short8*)wtf;
    const short8* wm = (const short8*)wmf;
    #pragma unroll
    for (int ks = 0; ks < 4; ++ks) {
        short8 bt[8], bm[8];
        #pragma unroll
        for (int nt = 0; nt < 8; ++nt) {
            bt[nt] = wt[(ks * 8 + nt) * 64 + lane];
            bm[nt] = wm[(ks * 8 + nt) * 64 + lane];
        }
        const int koff = ks * 32 + quad * 8;
        #pragma unroll
        for (int mt = 0; mt < 2; ++mt) {
            short8 af = *(const short8*)(aptr[mt] + koff);
            #pragma unroll
            for (int nt = 0; nt < 8; ++nt) {
                accP[mt][nt] = __builtin_amdgcn_mfma_f32_16x16x32_bf16(af, bt[nt], accP[mt][nt], 0, 0, 0);
                accQ[mt][nt] = __builtin_amdgcn_mfma_f32_16x16x32_bf16(af, bm[nt], accQ[mt][nt], 0, 0, 0);
            }
        }
    }

    #pragma unroll
    for (int mt = 0; mt < 2; ++mt)
        #pragma unroll
        for (int r = 0; r < 4; ++r) {
            int n = n0 + ew + mt * 16 + quad * 4 + r;
            size_t base = ((size_t)b * NP + n) * DD + l16;
            #pragma unroll
            for (int nt = 0; nt < 8; ++nt) {
                P[base + nt * 16] = f2bf(accP[mt][nt][r]);
                Q[base + nt * 16] = f2bf(accQ[mt][nt][r]);
            }
        }
}

// ---------------- edge kernel: mid = lrelu(P[row]+Q[col]+ds*w1last), GEMM2, seg-reduce ----------------
// 1D grid 5000 blocks; XCD-pair affinity: batch = (g>>1)&3.
// All P/Q gathers hoisted; mid held in regs; GEMM2 in two nt-halves to cap VGPR at 4 waves/EU.
__global__ __launch_bounds__(256, 4) void k_edge(
    const float* __restrict__ pos,
    const ushort* __restrict__ P, const ushort* __restrict__ Q,
    const int* __restrict__ rowS, const int* __restrict__ colS,
    const float* __restrict__ w1last,
    const ushort* __restrict__ w2f, const float* __restrict__ b2,
    float* __restrict__ aggr)
{
    __shared__ int    s_row[128];
    __shared__ int    s_col[128];
    __shared__ float  s_ds[128];
    __shared__ __align__(16) ushort s_red[128 * RSH];   // 17.4 KB

    const int g    = blockIdx.x;
    const int b    = (g >> 1) & 3;
    const int tile = (g >> 3) * 2 + (g & 1);
    const int e0   = tile * 128;
    const int t    = threadIdx.x;
    const int w    = t >> 6, lane = t & 63;
    const int quad = lane >> 4, l16 = lane & 15;

    if (t < 128) {
        int e = e0 + t;
        int r = rowS[e], c = colS[e];
        s_row[t] = r;
        s_col[t] = c;
        const float* pr = pos + ((size_t)b * NN + r) * 3;
        const float* pc = pos + ((size_t)b * NN + c) * 3;
        float dx = pr[0] - pc[0], dy = pr[1] - pc[1], dz = pr[2] - pc[2];
        s_ds[t] = dx * dx + dy * dy + dz * dz;
    }
    __syncthreads();

    const int ew = w * 32;
    const ushort* pp[2];
    const ushort* qp[2];
    float dsv[2];
    #pragma unroll
    for (int mt = 0; mt < 2; ++mt) {
        int el = ew + mt * 16 + l16;
        pp[mt]  = P + ((size_t)b * NP + s_row[el]) * DD;
        qp[mt]  = Q + ((size_t)b * NP + s_col[el]) * DD;
        dsv[mt] = s_ds[el];
    }

    // issue ALL gathers up front (16 x 16B per lane) -> single overlappable stall
    short8 pf[2][4], qf[2][4];
    #pragma unroll
    for (int ks = 0; ks < 4; ++ks) {
        const int koff = ks * 32 + quad * 8;
        #pragma unroll
        for (int mt = 0; mt < 2; ++mt) {
            pf[mt][ks] = *(const short8*)(pp[mt] + koff);
            qf[mt][ks] = *(const short8*)(qp[mt] + koff);
        }
    }

    // mid = lrelu(P+Q+ds*w1last) in bf16 regs (32 VGPRs)
    short8 mid[2][4];
    #pragma unroll
    for (int ks = 0; ks < 4; ++ks) {
        const int koff = ks * 32 + quad * 8;
        floatx4 wl0 = *(const floatx4*)(w1last + koff);
        floatx4 wl1 = *(const floatx4*)(w1last + koff + 4);
        #pragma unroll
        for (int mt = 0; mt < 2; ++mt) {
            #pragma unroll
            for (int j = 0; j < 4; ++j) {
                float v = bf2f((ushort)pf[mt][ks][j]) + bf2f((ushort)qf[mt][ks][j]) + dsv[mt] * wl0[j];
                mid[mt][ks][j] = (short)f2bf(lrelu(v));
            }
            #pragma unroll
            for (int j = 0; j < 4; ++j) {
                float v = bf2f((ushort)pf[mt][ks][4 + j]) + bf2f((ushort)qf[mt][ks][4 + j]) + dsv[mt] * wl1[j];
                mid[mt][ks][4 + j] = (short)f2bf(lrelu(v));
            }
        }
    }

    float b2r[8];
    #pragma unroll
    for (int nt = 0; nt < 8; ++nt) b2r[nt] = b2[nt * 16 + l16];

    const short8* w2v = (const short8*)w2f;
    #pragma unroll
    for (int ph = 0; ph < 2; ++ph) {
        floatx4 acc[2][4];
        #pragma unroll
        for (int mt = 0; mt < 2; ++mt)
            #pragma unroll
            for (int ntl = 0; ntl < 4; ++ntl)
                #pragma unroll
                for (int r = 0; r < 4; ++r) acc[mt][ntl][r] = b2r[ph * 4 + ntl];

        #pragma unroll
        for (int ks = 0; ks < 4; ++ks) {
            short8 bf[4];
            #pragma unroll
            for (int ntl = 0; ntl < 4; ++ntl)
                bf[ntl] = w2v[(ks * 8 + ph * 4 + ntl) * 64 + lane];
            #pragma unroll
            for (int mt = 0; mt < 2; ++mt)
                #pragma unroll
                for (int ntl = 0; ntl < 4; ++ntl)
                    acc[mt][ntl] = __builtin_amdgcn_mfma_f32_16x16x32_bf16(mid[mt][ks], bf[ntl], acc[mt][ntl], 0, 0, 0);
        }

        // stash msg (bf16) in wave-private LDS rows, then segmented scan over sorted cols
        #pragma unroll
        for (int mt = 0; mt < 2; ++mt)
            #pragma unroll
            for (int ntl = 0; ntl < 4; ++ntl)
                #pragma unroll
                for (int r = 0; r < 4; ++r)
                    s_red[(ew + mt * 16 + quad * 4 + r) * RSH + ntl * 16 + l16] =
                        f2bf(lrelu(acc[mt][ntl][r]));

        const int d = ph * 64 + lane;
        float run = 0.0f;
        int prev = s_col[ew];
        for (int r = 0; r < 32; ++r) {
            int cid = s_col[ew + r];
            float v = bf2f(s_red[(ew + r) * RSH + lane]);
            if (cid != prev) {
                atomicAdd(&aggr[((size_t)b * NP + prev) * DD + d], run);
                run = 0.0f;
                prev = cid;
            }
            run += v;
        }
        atomicAdd(&aggr[((size_t)b * NP + prev) * DD + d], run);
    }
}

// ---------------- node MLP (fused aggr-mean + coord update + residual + next-layer P/Q) ----------------
__global__ __launch_bounds__(256) void k_node(
    ushort* hb, float* aggr, const float* __restrict__ cnt,
    const float* __restrict__ cw, const float* __restrict__ cb,
    const ushort* __restrict__ w1f, const float* __restrict__ b1,
    const ushort* __restrict__ w2f, const float* __restrict__ b2,
    float* h, float* __restrict__ pos,
    int do_pq,
    const ushort* __restrict__ wtn, const ushort* __restrict__ wmn,
    const float* __restrict__ b1n,
    ushort* __restrict__ P, ushort* __restrict__ Q)
{
    __shared__ __align__(16) ushort s_mid[128 * MSTR];

    const int b    = blockIdx.y;
    const int n0   = blockIdx.x * 128;
    const int t    = threadIdx.x;
    const int w    = t >> 6, lane = t & 63;
    const int quad = lane >> 4, l16 = lane & 15;
    const int ew   = w * 32;

    const ushort* hptr[2];
    float* aptr[2];
    float inv[2];
    #pragma unroll
    for (int mt = 0; mt < 2; ++mt) {
        int node = n0 + ew + mt * 16 + l16;
        size_t base = ((size_t)b * NP + node) * DD;
        hptr[mt] = hb + base;
        aptr[mt] = aggr + base;
        if (node < NN) { float dn = cnt[node]; dn = dn > 1.0f ? dn : 1.0f; inv[mt] = 1.0f / dn; }
        else inv[mt] = 0.0f;
    }
    float b1r[8], b2r[8];
    #pragma unroll
    for (int nt = 0; nt < 8; ++nt) {
        int d = nt * 16 + l16;
        b1r[nt] = b1[d]; b2r[nt] = b2[d];
    }

    floatx4 acc[2][8];
    #pragma unroll
    for (int mt = 0; mt < 2; ++mt)
        #pragma unroll
        for (int nt = 0; nt < 8; ++nt)
            #pragma unroll
            for (int r = 0; r < 4; ++r) acc[mt][nt][r] = b1r[nt];

    float cwacc[2] = {0.0f, 0.0f};
    const floatx4 zero4 = {0.0f, 0.0f, 0.0f, 0.0f};
    const short8* w1v = (const short8*)w1f;
    #pragma unroll
    for (int ks = 0; ks < 8; ++ks) {
        short8 bf[8];
        #pragma unroll
        for (int nt = 0; nt < 8; ++nt) bf[nt] = w1v[(ks * 8 + nt) * 64 + lane];
        const int koff = (ks & 3) * 32 + quad * 8;
        if (ks < 4) {
            #pragma unroll
            for (int mt = 0; mt < 2; ++mt) {
                short8 af = *(const short8*)(hptr[mt] + koff);
                #pragma unroll
                for (int nt = 0; nt < 8; ++nt)
                    acc[mt][nt] = __builtin_amdgcn_mfma_f32_16x16x32_bf16(af, bf[nt], acc[mt][nt], 0, 0, 0);
            }
        } else {
            floatx4 cw0 = *(const floatx4*)(cw + koff);
            floatx4 cw1 = *(const floatx4*)(cw + koff + 4);
            #pragma unroll
            for (int mt = 0; mt < 2; ++mt) {
                floatx4 a0 = *(const floatx4*)(aptr[mt] + koff);
                floatx4 a1 = *(const floatx4*)(aptr[mt] + koff + 4);
                // self-clean aggr for next layer (replaces hipMemsetAsync)
                *(floatx4*)(aptr[mt] + koff)     = zero4;
                *(floatx4*)(aptr[mt] + koff + 4) = zero4;
                short8 af;
                #pragma unroll
                for (int j = 0; j < 4; ++j) {
                    float v = a0[j] * inv[mt];
                    af[j] = (short)f2bf(v);
                    cwacc[mt] += v * cw0[j];
                }
                #pragma unroll
                for (int j = 0; j < 4; ++j) {
                    float v = a1[j] * inv[mt];
                    af[4 + j] = (short)f2bf(v);
                    cwacc[mt] += v * cw1[j];
                }
                #pragma unroll
                for (int nt = 0; nt < 8; ++nt)
                    acc[mt][nt] = __builtin_amdgcn_mfma_f32_16x16x32_bf16(af, bf[nt], acc[mt][nt], 0, 0, 0);
            }
        }
    }

    // coord update: reduce cw-dot across quads
    float cb0 = cb[0];
    #pragma unroll
    for (int mt = 0; mt < 2; ++mt) {
        float full = cwacc[mt];
        full += __shfl_xor(full, 16);
        full += __shfl_xor(full, 32);
        int node = n0 + ew + mt * 16 + l16;
        if (quad == 0 && node < NN) {
            float cu = 0.1f * tanhf(full + cb0);
            float* pp = pos + ((size_t)b * NN + node) * 3;
            pp[0] += cu; pp[1] += cu; pp[2] += cu;
        }
    }

    #pragma unroll
    for (int mt = 0; mt < 2; ++mt)
        #pragma unroll
        for (int nt = 0; nt < 8; ++nt)
            #pragma unroll
            for (int r = 0; r < 4; ++r)
                s_mid[(ew + mt * 16 + quad * 4 + r) * MSTR + nt * 16 + l16] =
                    f2bf(lrelu(acc[mt][nt][r]));

    floatx4 acc2[2][8];
    #pragma unroll
    for (int mt = 0; mt < 2; ++mt)
        #pragma unroll
        for (int nt = 0; nt < 8; ++nt)
            #pragma unroll
            for (int r = 0; r < 4; ++r) acc2[mt][nt][r] = b2r[nt];

    const short8* w2v = (const short8*)w2f;
    #pragma unroll
    for (int ks = 0; ks < 4; ++ks) {
        short8 bf[8];
        #pragma unroll
        for (int nt = 0; nt < 8; ++nt) bf[nt] = w2v[(ks * 8 + nt) * 64 + lane];
        const int koff = ks * 32 + quad * 8;
        #pragma unroll
        for (int mt = 0; mt < 2; ++mt) {
            short8 af = *(const short8*)(&s_mid[(ew + mt * 16 + l16) * MSTR + koff]);
            #pragma unroll
            for (int nt = 0; nt < 8; ++nt)
                acc2[mt][nt] = __builtin_amdgcn_mfma_f32_16x16x32_bf16(af, bf[nt], acc2[mt][nt], 0, 0, 0);
        }
    }

    // h += lrelu(.): write fp32 master + bf16 copy; also stash new h in s_mid (wave-private rows)
    #pragma unroll
    for (int mt = 0; mt < 2; ++mt)
        #pragma unroll
        for (int r = 0; r < 4; ++r) {
            int rloc = ew + mt * 16 + quad * 4 + r;
            int n = n0 + rloc;
            size_t base = ((size_t)b * NP + n) * DD;
            #pragma unroll
            for (int nt = 0; nt < 8; ++nt) {
                int d = nt * 16 + l16;
                float hv = h[base + d] + lrelu(acc2[mt][nt][r]);   // pad rows: h==0, result unused
                ushort hvb = f2bf(hv);
                s_mid[rloc * MSTR + d] = hvb;
                if (n < NN) {
                    h[base + d] = hv;
                    hb[base + d] = hvb;
                }
            }
        }

    // fused next-layer P/Q from s_mid (wave-private rows -> no barrier)
    if (do_pq) {
        float b1nr[8];
        #pragma unroll
        for (int nt = 0; nt < 8; ++nt) b1nr[nt] = b1n[nt * 16 + l16];

        const short8* wt = (const short8*)wtn;
        floatx4 ap[2][8];
        #pragma unroll
        for (int mt = 0; mt < 2; ++mt)
            #pragma unroll
            for (int nt = 0; nt < 8; ++nt)
                #pragma unroll
                for (int r = 0; r < 4; ++r) ap[mt][nt][r] = 0.0f;
        #pragma unroll
        for (int ks = 0; ks < 4; ++ks) {
            short8 bt[8];
            #pragma unroll
            for (int nt = 0; nt < 8; ++nt) bt[nt] = wt[(ks * 8 + nt) * 64 + lane];
            const int koff = ks * 32 + quad * 8;
            #pragma unroll
            for (int mt = 0; mt < 2; ++mt) {
                short8 af = *(const short8*)(&s_mid[(ew + mt * 16 + l16) * MSTR + koff]);
                #pragma unroll
                for (int nt = 0; nt < 8; ++nt)
                    ap[mt][nt] = __builtin_amdgcn_mfma_f32_16x16x32_bf16(af, bt[nt], ap[mt][nt], 0, 0, 0);
            }
        }
        #pragma unroll
        for (int mt = 0; mt < 2; ++mt)
            #pragma unroll
            for (int r = 0; r < 4; ++r) {
                size_t base = ((size_t)b * NP + n0 + ew + mt * 16 + quad * 4 + r) * DD + l16;
                #pragma unroll
                for (int nt = 0; nt < 8; ++nt)
                    P[base + nt * 16] = f2bf(ap[mt][nt][r]);
            }

        const short8* wm = (const short8*)wmn;
        #pragma unroll
        for (int mt = 0; mt < 2; ++mt)
            #pragma unroll
            for (int nt = 0; nt < 8; ++nt)
                #pragma unroll
                for (int r = 0; r < 4; ++r) ap[mt][nt][r] = b1nr[nt];
        #pragma unroll
        for (int ks = 0; ks < 4; ++ks) {
            short8 bm[8];
            #pragma unroll
            for (int nt = 0; nt < 8; ++nt) bm[nt] = wm[(ks * 8 + nt) * 64 + lane];
            const int koff = ks * 32 + quad * 8;
            #pragma unroll
            for (int mt = 0; mt < 2; ++mt) {
                short8 af = *(const short8*)(&s_mid[(ew + mt * 16 + l16) * MSTR + koff]);
                #pragma unroll
                for (int nt = 0; nt < 8; ++nt)
                    ap[mt][nt] = __builtin_amdgcn_mfma_f32_16x16x32_bf16(af, bm[nt], ap[mt][nt], 0, 0, 0);
            }
        }
        #pragma unroll
        for (int mt = 0; mt < 2; ++mt)
            #pragma unroll
            for (int r = 0; r < 4; ++r) {
                size_t base = ((size_t)b * NP + n0 + ew + mt * 16 + quad * 4 + r) * DD + l16;
                #pragma unroll
                for (int nt = 0; nt < 8; ++nt)
                    Q[base + nt * 16] = f2bf(ap[mt][nt][r]);
            }
    }
}

#define NPC 50
__global__ void k_mean(const float* __restrict__ h, float* __restrict__ hm) {
    int b  = blockIdx.y;
    int n0 = blockIdx.x * NPC;
    int d  = threadIdx.x;
    float s = 0.0f;
    for (int n = n0; n < n0 + NPC; ++n) s += h[((size_t)b * NP + n) * DD + d];
    atomicAdd(&hm[b * DD + d], s);
}

__global__ void k_proj(const float* __restrict__ hm, const float* __restrict__ wp,
                       const float* __restrict__ bp, float* __restrict__ out) {
    int t = threadIdx.x;
    int b = t >> 6, o = t & (OUTD - 1);
    float s = 0.0f;
    for (int d2 = 0; d2 < DD; ++d2) s += hm[b * DD + d2] * wp[d2 * OUTD + o];
    s = s * (1.0f / NN) + bp[o];
    out[b * OUTD + o] = lrelu(s);
}

extern "C" void kernel_launch(void* const* d_in, const int* in_sizes, int n_in,
                              void* d_out, int out_size, void* d_ws, size_t ws_size,
                              hipStream_t stream) {
    (void)in_sizes; (void)n_in; (void)out_size; (void)ws_size;
    const float* x   = (const float*)d_in[0];
    const int*   ei  = (const int*)d_in[1];
    const float* w0  = (const float*)d_in[2];
    const float* b0  = (const float*)d_in[3];
    const float* ew1 = (const float*)d_in[4];
    const float* eb1 = (const float*)d_in[5];
    const float* ew2 = (const float*)d_in[6];
    const float* eb2 = (const float*)d_in[7];
    const float* cw  = (const float*)d_in[8];
    const float* cb  = (const float*)d_in[9];
    const float* nw1 = (const float*)d_in[10];
    const float* nb1 = (const float*)d_in[11];
    const float* nw2 = (const float*)d_in[12];
    const float* nb2 = (const float*)d_in[13];
    const float* wp  = (const float*)d_in[14];
    const float* bp  = (const float*)d_in[15];
    const int* row = ei;
    const int* col = ei + EE;

    const size_t HSZ = (size_t)BB * NP * DD;
    float* ws   = (float*)d_ws;
    float* h    = ws;
    float* aggr = h + HSZ;
    float* pos  = aggr + HSZ;
    float* cnt  = pos + (size_t)BB * NN * 3;
    float* hm   = cnt + NN;
    ushort* hb    = (ushort*)(hm + 512);
    ushort* Pb    = hb + HSZ;
    ushort* Qb    = Pb + HSZ;
    ushort* wtopf = Qb + HSZ;                           // LL*16384
    ushort* wmidf = wtopf + (size_t)LL * 16384;
    ushort* ew2f  = wmidf + (size_t)LL * 16384;
    ushort* nw1f  = ew2f + (size_t)LL * 16384;          // LL*32768
    ushort* nw2f  = nw1f + (size_t)LL * 32768;
    int* ecnt   = (int*)(nw2f + (size_t)LL * 16384);
    int* cursor = ecnt + NN;
    int* rowS   = cursor + NN;
    int* colS   = rowS + EE;

    hipMemcpyAsync(pos, x, sizeof(float) * (size_t)BB * NN * 3,
                   hipMemcpyDeviceToDevice, stream);
    hipMemsetAsync(cnt, 0, sizeof(float) * NN, stream);
    hipMemsetAsync(ecnt, 0, sizeof(int) * NN, stream);
    hipMemsetAsync(hm, 0, sizeof(float) * BB * DD, stream);
    hipMemsetAsync(aggr, 0, sizeof(float) * HSZ, stream);   // layers 1..3 self-cleaned by k_node

    k_cvtw<<<(LL * 4 * 512 + 255) / 256, 256, 0, stream>>>(ew1, wtopf, 257, 4);
    k_cvtw<<<(LL * 4 * 512 + 255) / 256, 256, 0, stream>>>(ew1 + (size_t)128 * DD, wmidf, 257, 4);
    k_cvtw<<<(LL * 4 * 512 + 255) / 256, 256, 0, stream>>>(ew2, ew2f, 128, 4);
    k_cvtw<<<(LL * 8 * 512 + 255) / 256, 256, 0, stream>>>(nw1, nw1f, 256, 8);
    k_cvtw<<<(LL * 4 * 512 + 255) / 256, 256, 0, stream>>>(nw2, nw2f, 128, 4);

    k_h0<<<((int)HSZ + 255) / 256, 256, 0, stream>>>(x, w0, b0, h, hb);
    k_count<<<(EE + 255) / 256, 256, 0, stream>>>(col, cnt, ecnt);
    k_scan<<<1, 256, 0, stream>>>(ecnt, cursor);
    k_place<<<(EE + 255) / 256, 256, 0, stream>>>(row, col, cursor, rowS, colS);

    k_pq<<<dim3(NP / 128, BB), 256, 0, stream>>>(hb, wtopf, wmidf, eb1, Pb, Qb);

    for (int i = 0; i < LL; ++i) {
        k_edge<<<(EE / 128) * BB, 256, 0, stream>>>(
            pos, Pb, Qb, rowS, colS,
            ew1 + (size_t)i * 257 * DD + (size_t)256 * DD,
            ew2f + (size_t)i * 16384,
            eb2 + (size_t)i * DD,
            aggr);
        int nx = (i < LL - 1) ? (i + 1) : i;
        k_node<<<dim3(NP / 128, BB), 256, 0, stream>>>(
            hb, aggr, cnt,
            cw + (size_t)i * DD, cb + i,
            nw1f + (size_t)i * 32768, nb1 + (size_t)i * DD,
            nw2f + (size_t)i * 16384, nb2 + (size_t)i * DD,
            h, pos,
            (i < LL - 1) ? 1 : 0,
            wtopf + (size_t)nx * 16384, wmidf + (size_t)nx * 16384,
            eb1 + (size_t)nx * DD,
            Pb, Qb);
    }

    k_mean<<<dim3(NN / NPC, BB), DD, 0, stream>>>(h, hm);
    k_proj<<<1, 256, 0, stream>>>(hm, wp, bp, (float*)d_out);
}